// Round 1
// baseline (483.122 us; speedup 1.0000x reference)
//
#include <hip/hip_runtime.h>
#include <hip/hip_bf16.h>
#include <math.h>

#define T_TOKENS 16384
#define H_DIM    2880
#define KHALF    1440      // fb kernel: H_DIM/2
#define E_EXP    128
#define TOPK     4
#define MT       32        // tokens per block
#define KC       32        // fb kernel K chunk
#define KQ       720       // H_DIM/4, per-quarter K (main kernel)
#define NIT      45        // KQ/16 iterations
#define NC16     180       // H_DIM/16 chunks in wsW
#define EPS_GAP  5e-4f

// d_ws layout (prep path):
//   [0..63]                : flag_count (int at offset 0) + pad
//   [64 .. 64+1.44MB)      : W frags, [c16 chunk][frag nf*2+s][lane] uint4
//   [then]                 : flag_list (T_TOKENS ints)
#define WS_WOFF   64
#define WS_WBYTES (NC16 * 512 * 16)
#define WS_FLOFF  (WS_WOFF + WS_WBYTES)
#define WS_NEED   (WS_FLOFF + T_TOKENS * 4)

typedef __bf16 bf16x8 __attribute__((ext_vector_type(8)));
typedef float  f32x4  __attribute__((ext_vector_type(4)));
typedef float  f32x16 __attribute__((ext_vector_type(16)));

// packed RNE split: (a,b) -> hi word [b_hi|a_hi], lo word [b_lo|a_lo]
__device__ __forceinline__ void split2(float a, float b,
                                       unsigned int& hi, unsigned int& lo) {
    float2 p; p.x = a; p.y = b;
    __hip_bfloat162 h = __float22bfloat162_rn(p);
    unsigned int hu; __builtin_memcpy(&hu, &h, 4);
    float2 r;
    r.x = a - __uint_as_float((hu & 0xffffu) << 16);
    r.y = b - __uint_as_float(hu & 0xffff0000u);
    __hip_bfloat162 l = __float22bfloat162_rn(r);
    unsigned int lu; __builtin_memcpy(&lu, &l, 4);
    hi = hu; lo = lu;
}

// ---------------------------------------------------------------------------
// Prep: split W into 32x32x16-fragment-ordered bf16 hi/lo.
// Chunk c16 covers k in [c16*16, c16*16+16). Frag fr = nf*2 + s (s=0 hi, 1 lo).
// Frag lane L: e = nf*32 + (L&31), k = c16*16 + (L>>5)*8 + j (j=0..7).
// ---------------------------------------------------------------------------
__global__ __launch_bounds__(256) void prep_w(const float* __restrict__ W,
                                              uint4* __restrict__ wsW) {
    const int f   = blockIdx.x * 256 + threadIdx.x;   // 0 .. 46079
    const int c16 = f >> 8;          // 0..179
    const int rem = f & 255;
    const int nf  = rem >> 6;        // 0..3
    const int kg  = (rem >> 5) & 1;  // 0..1
    const int e5  = rem & 31;
    const int e   = nf * 32 + e5;
    const int k   = c16 * 16 + kg * 8;
    const int L   = kg * 32 + e5;
    const float* p = W + (size_t)e * H_DIM + k;
    const float4 x0 = *(const float4*)p;
    const float4 x1 = *(const float4*)(p + 4);
    uint4 hi, lo;
    split2(x0.x, x0.y, hi.x, lo.x);
    split2(x0.z, x0.w, hi.y, lo.y);
    split2(x1.x, x1.y, hi.z, lo.z);
    split2(x1.z, x1.w, hi.w, lo.w);
    wsW[(size_t)c16 * 512 + (nf * 2 + 0) * 64 + L] = hi;
    wsW[(size_t)c16 * 512 + (nf * 2 + 1) * 64 + L] = lo;
}

// ---------------------------------------------------------------------------
// Main: bf16x3 MFMA GEMM with 32x32x16, in-block split-K over 4 quarters,
// stage-ahead single-barrier double-buffer (W via global_load_lds width 16,
// A via reg prefetch + split2 + one contiguous ds_write_b128 per thread).
// Waves: (q = wave>>1) in 0..3 K-quarter, (half = wave&1):
//   staging: half selects hi/lo A part and W frag group;
//   compute: half selects expert half (64 experts), 2 n-frags of 32.
// LDS: 64 KB W dbuf + 16 KB A dbuf = 80 KB; logits overlay -> 2 blocks/CU.
// ---------------------------------------------------------------------------
__global__ __launch_bounds__(512, 4) void router_main(
    const float* __restrict__ A, const uint4* __restrict__ wsW,
    const float* __restrict__ bias, float* __restrict__ out,
    int* __restrict__ flag_count, int* __restrict__ flag_list)
{
    union SMem {
        struct {
            uint4 W [2][4][8][64];   // [buf][q][frag nf*2+s][lane]  64 KB
            uint4 Af[2][4][2][64];   // [buf][q][s][lane]            16 KB
        } s;
        struct {
            float L0[MT][129];       // partial logits q0+q1         16.5 KB
            float L1[MT][129];       // partial logits q2+q3         16.5 KB
        } r;
    };
    __shared__ SMem sm;

    const int tid    = threadIdx.x;
    const int t_base = blockIdx.x * MT;
    const int wave = tid >> 6;
    const int l    = tid & 63;
    const int q    = wave >> 1;     // K quarter (staging + compute)
    const int half = wave & 1;      // staging: hi/lo; compute: expert half
    const int tok  = l & 31;
    const int kg   = l >> 5;

    // A staging source: lane l covers A[t_base+tok][q*KQ + it*16 + kg*8 .. +7]
    const float* Ag = A + (size_t)(t_base + tok) * H_DIM + q * KQ + kg * 8;
    // W staging source: wave stages frags half*4 .. half*4+3 of quarter q
    const uint4* wsrc = wsW + (size_t)q * (NIT * 512) + (half * 4) * 64 + l;

    f32x16 acc[2];
#pragma unroll
    for (int i = 0; i < 2; ++i)
#pragma unroll
        for (int r = 0; r < 16; ++r) acc[i][r] = 0.0f;

#define STAGE_AW(NB, IT1)                                                      \
    {                                                                          \
        uint4 hi4, lo4;                                                        \
        split2(av0.x, av0.y, hi4.x, lo4.x);                                    \
        split2(av0.z, av0.w, hi4.y, lo4.y);                                    \
        split2(av1.x, av1.y, hi4.z, lo4.z);                                    \
        split2(av1.z, av1.w, hi4.w, lo4.w);                                    \
        sm.s.Af[NB][q][half][l] = half ? lo4 : hi4;                            \
        const uint4* wc = wsrc + (size_t)(IT1) * 512;                          \
        _Pragma("unroll")                                                      \
        for (int j = 0; j < 4; ++j) {                                          \
            __builtin_amdgcn_global_load_lds(                                  \
                (const __attribute__((address_space(1))) void*)(wc + j * 64),  \
                (__attribute__((address_space(3))) void*)&sm.s.W[NB][q][half * 4 + j][0], \
                16, 0, 0);                                                     \
        }                                                                      \
    }

    // prologue: stage chunk 0 into buf 0, prefetch A chunk 1
    float4 av0 = *(const float4*)(Ag);
    float4 av1 = *(const float4*)(Ag + 4);
    STAGE_AW(0, 0);
    av0 = *(const float4*)(Ag + 16);
    av1 = *(const float4*)(Ag + 20);
    __syncthreads();

    int b = 0;
    for (int it = 0; it < NIT; ++it) {
        // stage next chunk into the other buffer (overlaps with compute below)
        if (it + 1 < NIT) {
            STAGE_AW(b ^ 1, it + 1);
            if (it + 2 < NIT) {
                av0 = *(const float4*)(Ag + (it + 2) * 16);
                av1 = *(const float4*)(Ag + (it + 2) * 16 + 4);
            }
        }
        // compute current buffer: 6 ds_read_b128 + 6 MFMA 32x32x16
        const bf16x8 ahi = *(const bf16x8*)&sm.s.Af[b][q][0][l];
        const bf16x8 alo = *(const bf16x8*)&sm.s.Af[b][q][1][l];
#pragma unroll
        for (int n = 0; n < 2; ++n) {
            const int fr = (half * 2 + n) * 2;
            const bf16x8 whi = *(const bf16x8*)&sm.s.W[b][q][fr][l];
            const bf16x8 wlo = *(const bf16x8*)&sm.s.W[b][q][fr + 1][l];
            acc[n] = __builtin_amdgcn_mfma_f32_32x32x16_bf16(ahi, whi, acc[n], 0, 0, 0);
            acc[n] = __builtin_amdgcn_mfma_f32_32x32x16_bf16(ahi, wlo, acc[n], 0, 0, 0);
            acc[n] = __builtin_amdgcn_mfma_f32_32x32x16_bf16(alo, whi, acc[n], 0, 0, 0);
        }
        __syncthreads();   // vmcnt(0)+lgkmcnt(0) drain lands AFTER compute
        b ^= 1;
    }

    // epilogue: C/D layout col(expert)=l&31, row(token)=(r&3)+8*(r>>2)+4*(l>>5)
    // split-K reduction: q0,q2 write partials; q1,q3 add; topk reads L0+L1.
    if (q == 0 || q == 2) {
        float (*Ld)[129] = (q == 0) ? sm.r.L0 : sm.r.L1;
#pragma unroll
        for (int n = 0; n < 2; ++n) {
            const int e = half * 64 + n * 32 + (l & 31);
            const float bv = (q == 0) ? bias[e] : 0.0f;
#pragma unroll
            for (int r = 0; r < 16; ++r) {
                const int trow = (r & 3) + 8 * (r >> 2) + 4 * (l >> 5);
                Ld[trow][e] = acc[n][r] + bv;
            }
        }
    }
    __syncthreads();
    if (q == 1 || q == 3) {
        float (*Ld)[129] = (q == 1) ? sm.r.L0 : sm.r.L1;
#pragma unroll
        for (int n = 0; n < 2; ++n) {
            const int e = half * 64 + n * 32 + (l & 31);
#pragma unroll
            for (int r = 0; r < 16; ++r) {
                const int trow = (r & 3) + 8 * (r >> 2) + 4 * (l >> 5);
                Ld[trow][e] += acc[n][r];
            }
        }
    }
    __syncthreads();

    // top-5 scan (stable strict '>') + gap test + softmax
    if (tid < MT) {
        float v0 = -1e30f, v1 = -1e30f, v2 = -1e30f, v3 = -1e30f, v4 = -1e30f;
        int   i0 = 0, i1 = 0, i2 = 0, i3 = 0, i4 = 0;
        for (int e = 0; e < E_EXP; ++e) {
            const float x = sm.r.L0[tid][e] + sm.r.L1[tid][e];
            if (x > v4) {
                if (x > v0)      { v4=v3;i4=i3; v3=v2;i3=i2; v2=v1;i2=i1; v1=v0;i1=i0; v0=x;i0=e; }
                else if (x > v1) { v4=v3;i4=i3; v3=v2;i3=i2; v2=v1;i2=i1; v1=x;i1=e; }
                else if (x > v2) { v4=v3;i4=i3; v3=v2;i3=i2; v2=x;i2=e; }
                else if (x > v3) { v4=v3;i4=i3; v3=x;i3=e; }
                else             { v4=x;i4=e; }
            }
        }
        const float g0 = v0 - v1, g1 = v1 - v2, g2 = v2 - v3, g3 = v3 - v4;
        float mg = g0 < g1 ? g0 : g1;
        mg = mg < g2 ? mg : g2;
        mg = mg < g3 ? mg : g3;

        const float e0x = expf(v0 - v0);
        const float e1x = expf(v1 - v0);
        const float e2x = expf(v2 - v0);
        const float e3x = expf(v3 - v0);
        const float s   = e0x + e1x + e2x + e3x;

        const int gt = t_base + tid;
        float* out_scores = out;
        float* out_idx    = out + (size_t)T_TOKENS * TOPK;
        out_scores[gt * 4 + 0] = e0x / s;
        out_scores[gt * 4 + 1] = e1x / s;
        out_scores[gt * 4 + 2] = e2x / s;
        out_scores[gt * 4 + 3] = e3x / s;
        out_idx[gt * 4 + 0] = (float)i0;
        out_idx[gt * 4 + 1] = (float)i1;
        out_idx[gt * 4 + 2] = (float)i2;
        out_idx[gt * 4 + 3] = (float)i3;

        if (mg < EPS_GAP) {
            const int p = atomicAdd(flag_count, 1);
            if (p < T_TOKENS) flag_list[p] = gt;
        }
    }
#undef STAGE_AW
}

// ---------------------------------------------------------------------------
// Fallback main (ws too small for prep path): round-4 kernel, unchanged.
// ---------------------------------------------------------------------------
__global__ __launch_bounds__(512, 4) void router_main_fb(
    const float* __restrict__ A, const float* __restrict__ W,
    const float* __restrict__ bias, float* __restrict__ out,
    int* __restrict__ flag_count, int* __restrict__ flag_list)
{
    __shared__ __align__(16) uint2 sAhi[2][2][128];
    __shared__ __align__(16) uint2 sAlo[2][2][128];
    __shared__ __align__(16) uint4 sWhi[2][8][64];
    __shared__ __align__(16) uint4 sWlo[2][8][64];
    __shared__ float sL[MT][129];

    const int tid    = threadIdx.x;
    const int t_base = blockIdx.x * MT;
    const int wave  = tid >> 6;
    const int L     = tid & 63;
    const int whalf = wave >> 2;
    const int wm    = wave & 1;
    const int wn    = (wave >> 1) & 1;
    const int shalf = tid >> 8;
    const int tid_h = tid & 255;
    const int at = tid_h >> 3;
    const int ac = tid_h & 7;
    const int a_idx = (at >> 4) * 128 + ((((ac >> 1) << 4) | (at & 15)) << 1) + (ac & 1);
    const float* Ag = A + (size_t)(t_base + at) * H_DIM + shalf * KHALF + ac * 4;
    const int we  = tid_h >> 1;
    const int wq0 = (tid_h & 1) * 2;
    const float* Wg = W + (size_t)we * H_DIM + shalf * KHALF + wq0 * 8;
    const int w_nt = we >> 4;
    const int w_n  = we & 15;

    uint2* sAhiF = &sAhi[shalf][0][0];
    uint2* sAloF = &sAlo[shalf][0][0];

    f32x4 acc[4];
#pragma unroll
    for (int i = 0; i < 4; ++i) { f32x4 z = {0.f, 0.f, 0.f, 0.f}; acc[i] = z; }

    for (int k0 = 0; k0 < KHALF; k0 += KC) {
        const float4 av  = *(const float4*)(Ag + k0);
        const float4 wv0 = *(const float4*)(Wg + k0);
        const float4 wv1 = *(const float4*)(Wg + k0 + 4);
        const float4 wv2 = *(const float4*)(Wg + k0 + 8);
        const float4 wv3 = *(const float4*)(Wg + k0 + 12);

        uint2 ahp, alp;
        split2(av.x, av.y, ahp.x, alp.x);
        split2(av.z, av.w, ahp.y, alp.y);
        uint4 whp0, wlp0, whp1, wlp1;
        split2(wv0.x, wv0.y, whp0.x, wlp0.x);
        split2(wv0.z, wv0.w, whp0.y, wlp0.y);
        split2(wv1.x, wv1.y, whp0.z, wlp0.z);
        split2(wv1.z, wv1.w, whp0.w, wlp0.w);
        split2(wv2.x, wv2.y, whp1.x, wlp1.x);
        split2(wv2.z, wv2.w, whp1.y, wlp1.y);
        split2(wv3.x, wv3.y, whp1.z, wlp1.z);
        split2(wv3.z, wv3.w, whp1.w, wlp1.w);

        __syncthreads();
        sAhiF[a_idx] = ahp;
        sAloF[a_idx] = alp;
        sWhi[shalf][w_nt][((wq0 + 0) << 4) | w_n] = whp0;
        sWhi[shalf][w_nt][((wq0 + 1) << 4) | w_n] = whp1;
        sWlo[shalf][w_nt][((wq0 + 0) << 4) | w_n] = wlp0;
        sWlo[shalf][w_nt][((wq0 + 1) << 4) | w_n] = wlp1;
        __syncthreads();

        const bf16x8 ahi = *(const bf16x8*)&sAhi[whalf][wm][L * 2];
        const bf16x8 alo = *(const bf16x8*)&sAlo[whalf][wm][L * 2];
#pragma unroll
        for (int i = 0; i < 4; ++i) {
            const int nt = wn * 4 + i;
            const bf16x8 whi = *(const bf16x8*)&sWhi[whalf][nt][L];
            const bf16x8 wlo = *(const bf16x8*)&sWlo[whalf][nt][L];
            acc[i] = __builtin_amdgcn_mfma_f32_16x16x32_bf16(ahi, whi, acc[i], 0, 0, 0);
            acc[i] = __builtin_amdgcn_mfma_f32_16x16x32_bf16(ahi, wlo, acc[i], 0, 0, 0);
            acc[i] = __builtin_amdgcn_mfma_f32_16x16x32_bf16(alo, whi, acc[i], 0, 0, 0);
        }
    }

    __syncthreads();
    if (whalf == 0) {
#pragma unroll
        for (int i = 0; i < 4; ++i) {
            const int e = wn * 64 + i * 16 + (L & 15);
            const float b = bias[e];
#pragma unroll
            for (int r = 0; r < 4; ++r)
                sL[wm * 16 + (L >> 4) * 4 + r][e] = acc[i][r] + b;
        }
    }
    __syncthreads();
    if (whalf == 1) {
#pragma unroll
        for (int i = 0; i < 4; ++i) {
            const int e = wn * 64 + i * 16 + (L & 15);
#pragma unroll
            for (int r = 0; r < 4; ++r)
                sL[wm * 16 + (L >> 4) * 4 + r][e] += acc[i][r];
        }
    }
    __syncthreads();

    if (tid < MT) {
        float v0 = -1e30f, v1 = -1e30f, v2 = -1e30f, v3 = -1e30f, v4 = -1e30f;
        int   i0 = 0, i1 = 0, i2 = 0, i3 = 0, i4 = 0;
        for (int e = 0; e < E_EXP; ++e) {
            const float x = sL[tid][e];
            if (x > v4) {
                if (x > v0)      { v4=v3;i4=i3; v3=v2;i3=i2; v2=v1;i2=i1; v1=v0;i1=i0; v0=x;i0=e; }
                else if (x > v1) { v4=v3;i4=i3; v3=v2;i3=i2; v2=v1;i2=i1; v1=x;i1=e; }
                else if (x > v2) { v4=v3;i4=i3; v3=v2;i3=i2; v2=x;i2=e; }
                else if (x > v3) { v4=v3;i4=i3; v3=x;i3=e; }
                else             { v4=x;i4=e; }
            }
        }
        const float g0 = v0 - v1, g1 = v1 - v2, g2 = v2 - v3, g3 = v3 - v4;
        float mg = g0 < g1 ? g0 : g1;
        mg = mg < g2 ? mg : g2;
        mg = mg < g3 ? mg : g3;

        const float e0x = expf(v0 - v0);
        const float e1x = expf(v1 - v0);
        const float e2x = expf(v2 - v0);
        const float e3x = expf(v3 - v0);
        const float s   = e0x + e1x + e2x + e3x;

        const int gt = t_base + tid;
        float* out_scores = out;
        float* out_idx    = out + (size_t)T_TOKENS * TOPK;
        out_scores[gt * 4 + 0] = e0x / s;
        out_scores[gt * 4 + 1] = e1x / s;
        out_scores[gt * 4 + 2] = e2x / s;
        out_scores[gt * 4 + 3] = e3x / s;
        out_idx[gt * 4 + 0] = (float)i0;
        out_idx[gt * 4 + 1] = (float)i1;
        out_idx[gt * 4 + 2] = (float)i2;
        out_idx[gt * 4 + 3] = (float)i3;

        if (mg < EPS_GAP) {
            const int p = atomicAdd(flag_count, 1);
            if (p < T_TOKENS) flag_list[p] = gt;
        }
    }
}

// ---------------------------------------------------------------------------
// Recheck: exact f64 recompute of flagged tokens (unchanged).
// ---------------------------------------------------------------------------
__global__ __launch_bounds__(256) void router_recheck(
    const float* __restrict__ A, const float* __restrict__ W,
    const float* __restrict__ bias, float* __restrict__ out,
    const int* __restrict__ flag_count, const int* __restrict__ flag_list)
{
    __shared__ double sPart[256];
    __shared__ double sLog[E_EXP];

    int count = *flag_count;
    if (count > T_TOKENS) count = T_TOKENS;

    const int tid = threadIdx.x;
    const int e   = tid & (E_EXP - 1);
    const int h   = tid >> 7;          // K half: 0 or 1

    for (int i = blockIdx.x; i < count; i += gridDim.x) {
        const int t = flag_list[i];
        const float* arow = A + (size_t)t * H_DIM + h * KHALF;
        const float* wrow = W + (size_t)e * H_DIM + h * KHALF;

        double s0 = 0.0, s1 = 0.0, s2 = 0.0, s3 = 0.0;
        float4 a[8], w[8];
#pragma unroll
        for (int q = 0; q < 8; ++q) {
            a[q] = *(const float4*)(arow + q * 4);
            w[q] = *(const float4*)(wrow + q * 4);
        }
        for (int it = 0; it < KHALF / 32 - 1; ++it) {
            const float* ap = arow + (it + 1) * 32;
            const float* wp = wrow + (it + 1) * 32;
            float4 na[8], nw[8];
#pragma unroll
            for (int q = 0; q < 8; ++q) {
                na[q] = *(const float4*)(ap + q * 4);
                nw[q] = *(const float4*)(wp + q * 4);
            }
#pragma unroll
            for (int q = 0; q < 8; ++q) {
                s0 += (double)a[q].x * (double)w[q].x;
                s1 += (double)a[q].y * (double)w[q].y;
                s2 += (double)a[q].z * (double)w[q].z;
                s3 += (double)a[q].w * (double)w[q].w;
            }
#pragma unroll
            for (int q = 0; q < 8; ++q) { a[q] = na[q]; w[q] = nw[q]; }
        }
#pragma unroll
        for (int q = 0; q < 8; ++q) {
            s0 += (double)a[q].x * (double)w[q].x;
            s1 += (double)a[q].y * (double)w[q].y;
            s2 += (double)a[q].z * (double)w[q].z;
            s3 += (double)a[q].w * (double)w[q].w;
        }
        sPart[tid] = (s0 + s1) + (s2 + s3);
        __syncthreads();
        if (h == 0) sLog[e] = sPart[e] + sPart[e + 128] + (double)bias[e];
        __syncthreads();

        if (tid == 0) {
            double v0 = -1e300, v1 = -1e300, v2 = -1e300, v3 = -1e300;
            int    i0 = 0, i1 = 0, i2 = 0, i3 = 0;
            for (int q = 0; q < E_EXP; ++q) {
                const double x = sLog[q];
                if (x > v3) {
                    if (x > v0)      { v3=v2;i3=i2; v2=v1;i2=i1; v1=v0;i1=i0; v0=x;i0=q; }
                    else if (x > v1) { v3=v2;i3=i2; v2=v1;i2=i1; v1=x;i1=q; }
                    else if (x > v2) { v3=v2;i3=i2; v2=x;i2=q; }
                    else             { v3=x;i3=q; }
                }
            }
            const double e0x = exp(v0 - v0);
            const double e1x = exp(v1 - v0);
            const double e2x = exp(v2 - v0);
            const double e3x = exp(v3 - v0);
            const double s   = e0x + e1x + e2x + e3x;
            float* out_scores = out;
            float* out_idx    = out + (size_t)T_TOKENS * TOPK;
            out_scores[t * 4 + 0] = (float)(e0x / s);
            out_scores[t * 4 + 1] = (float)(e1x / s);
            out_scores[t * 4 + 2] = (float)(e2x / s);
            out_scores[t * 4 + 3] = (float)(e3x / s);
            out_idx[t * 4 + 0] = (float)i0;
            out_idx[t * 4 + 1] = (float)i1;
            out_idx[t * 4 + 2] = (float)i2;
            out_idx[t * 4 + 3] = (float)i3;
        }
        __syncthreads();
    }
}

extern "C" void kernel_launch(void* const* d_in, const int* in_sizes, int n_in,
                              void* d_out, int out_size, void* d_ws, size_t ws_size,
                              hipStream_t stream) {
    const float* A    = (const float*)d_in[0];
    const float* W    = (const float*)d_in[1];
    const float* bias = (const float*)d_in[2];
    float* out = (float*)d_out;

    if (ws_size >= (size_t)WS_NEED) {
        int*  flag_count = (int*)d_ws;
        int*  flag_list  = (int*)((char*)d_ws + WS_FLOFF);
        uint4* wsW       = (uint4*)((char*)d_ws + WS_WOFF);
        hipMemsetAsync(flag_count, 0, sizeof(int), stream);
        prep_w<<<dim3(NC16), dim3(256), 0, stream>>>(W, wsW);
        router_main<<<dim3(T_TOKENS / MT), dim3(512), 0, stream>>>(A, wsW, bias, out,
                                                                   flag_count, flag_list);
        router_recheck<<<dim3(512), dim3(256), 0, stream>>>(A, W, bias, out,
                                                            flag_count, flag_list);
    } else {
        int* flag_count = (int*)d_ws;
        int* flag_list  = (int*)d_ws + 1;
        hipMemsetAsync(flag_count, 0, sizeof(int), stream);
        router_main_fb<<<dim3(T_TOKENS / MT), dim3(512), 0, stream>>>(A, W, bias, out,
                                                                      flag_count, flag_list);
        router_recheck<<<dim3(512), dim3(256), 0, stream>>>(A, W, bias, out,
                                                            flag_count, flag_list);
    }
}

// Round 2
// 379.697 us; speedup vs baseline: 1.2724x; 1.2724x over previous
//
#include <hip/hip_runtime.h>
#include <hip/hip_bf16.h>
#include <math.h>

#define T_TOKENS 16384
#define H_DIM    2880
#define KHALF    1440      // H_DIM/2, per in-block K-split half
#define E_EXP    128
#define TOPK     4
#define MT       32        // tokens per block
#define KC       32        // K chunk per iteration
#define NCHUNK   (H_DIM / KC)          // 90
#define NCHUNK_H (KHALF / KC)          // 45
#define EPS_GAP  5e-4f

// d_ws layout (prep path):
//   [0..63]                : flag_count (int at offset 0) + pad
//   [64 .. 64+1.44MB)      : W frags, [chunk kc][hi:512 | lo:512 uint4]
//   [then]                 : flag_list (T_TOKENS ints)
#define WS_WOFF   64
#define WS_WBYTES (NCHUNK * 1024 * 16)
#define WS_FLOFF  (WS_WOFF + WS_WBYTES)
#define WS_NEED   (WS_FLOFF + T_TOKENS * 4)

typedef __bf16 bf16x8 __attribute__((ext_vector_type(8)));
typedef float  f32x4  __attribute__((ext_vector_type(4)));

// packed RNE split: (a,b) -> hi word [b_hi|a_hi], lo word [b_lo|a_lo]
__device__ __forceinline__ void split2(float a, float b,
                                       unsigned int& hi, unsigned int& lo) {
    float2 p; p.x = a; p.y = b;
    __hip_bfloat162 h = __float22bfloat162_rn(p);
    unsigned int hu; __builtin_memcpy(&hu, &h, 4);
    float2 r;
    r.x = a - __uint_as_float((hu & 0xffffu) << 16);
    r.y = b - __uint_as_float(hu & 0xffff0000u);
    __hip_bfloat162 l = __float22bfloat162_rn(r);
    unsigned int lu; __builtin_memcpy(&lu, &l, 4);
    hi = hu; lo = lu;
}

// ---------------------------------------------------------------------------
// Prep: split W into MFMA-fragment-ordered bf16 hi/lo (round-0 layout).
// Frag (kc, nt, L): e = nt*16 + (L&15), k = kc*32 + (L>>4)*8 .. +7.
// ---------------------------------------------------------------------------
__global__ __launch_bounds__(256) void prep_w(const float* __restrict__ W,
                                              uint4* __restrict__ wsW) {
    const int f   = blockIdx.x * 256 + threadIdx.x;   // 0 .. 46079
    const int kc  = f >> 9;
    const int rem = f & 511;
    const int nt  = rem >> 6;
    const int L   = rem & 63;
    const int e   = nt * 16 + (L & 15);
    const int k   = kc * KC + (L >> 4) * 8;
    const float* p = W + (size_t)e * H_DIM + k;
    const float4 x0 = *(const float4*)p;
    const float4 x1 = *(const float4*)(p + 4);
    uint4 hi, lo;
    split2(x0.x, x0.y, hi.x, lo.x);
    split2(x0.z, x0.w, hi.y, lo.y);
    split2(x1.x, x1.y, hi.z, lo.z);
    split2(x1.z, x1.w, hi.w, lo.w);
    wsW[(size_t)kc * 1024 + nt * 64 + L]       = hi;
    wsW[(size_t)kc * 1024 + 512 + nt * 64 + L] = lo;
}

// ---------------------------------------------------------------------------
// Main: round-0 compute (16x16x32 bf16x3, f32x4 acc[4], in-block split-K
// over 2 halves) + round-1 pipeline (stage-ahead double-buffer, ONE barrier
// per iteration, vmcnt drain lands after compute) + conflict-free linear A
// staging (256 threads x 32B -> 2 linear uint4 ds_writes each).
// LDS: W dbuf 64 KB + A dbuf 16 KB (sL overlaid) = 80 KB -> 2 blocks/CU.
// ---------------------------------------------------------------------------
__global__ __launch_bounds__(512, 4) void router_main(
    const float* __restrict__ A, const uint4* __restrict__ wsW,
    const float* __restrict__ bias, float* __restrict__ out,
    int* __restrict__ flag_count, int* __restrict__ flag_list)
{
    union SMem {
        struct {
            uint4 W  [2][2][1024];   // [buf][half][hi:512|lo:512 frags] 64 KB
            uint4 Ahi[2][2][2][64];  // [buf][half][wm][lane]             8 KB
            uint4 Alo[2][2][2][64];  //                                   8 KB
        } s;
        float L[MT][129];            // logits (epilogue only)         16.5 KB
    };
    __shared__ SMem sm;

    const int tid    = threadIdx.x;
    const int t_base = blockIdx.x * MT;

    const int wave  = tid >> 6;
    const int L     = tid & 63;
    const int whalf = wave >> 2;        // K half this wave computes
    const int wm    = wave & 1;         // m-tile
    const int wn    = (wave >> 1) & 1;  // n-half (4 n-tiles)

    // W staging roles (all 512 threads, same as round 0)
    const int shalf = tid >> 8;
    const int wv    = wave & 3;
    const uint4* wsrc = wsW + (size_t)(shalf * NCHUNK_H) * 1024 + (wv * 4) * 64 + L;

    // A staging roles (threads 0..255): t = tid&31 token, octet c = tid>>5:
    // half = c>>2, kq = c&3. Each thread: 32B load, split2 x4, 2 linear uint4
    // writes at frag position (kq<<4)|(t&15) -> conflict-free write AND read.
    const bool doA = tid < 256;
    const int at   = tid & 31;
    const int ac   = (tid >> 5) & 7;
    const int ah   = ac >> 2;
    const int akq  = ac & 3;
    const int awm  = at >> 4;
    const int aL   = (akq << 4) | (at & 15);
    const float* Ag = A + (size_t)(t_base + at) * H_DIM + ah * KHALF + akq * 8;

    f32x4 acc[4];
#pragma unroll
    for (int i = 0; i < 4; ++i) { f32x4 z = {0.f, 0.f, 0.f, 0.f}; acc[i] = z; }

#define STAGE(NB, IT)                                                          \
    {                                                                          \
        if (doA) {                                                             \
            uint4 hi4, lo4;                                                    \
            split2(av0.x, av0.y, hi4.x, lo4.x);                                \
            split2(av0.z, av0.w, hi4.y, lo4.y);                                \
            split2(av1.x, av1.y, hi4.z, lo4.z);                                \
            split2(av1.z, av1.w, hi4.w, lo4.w);                                \
            sm.s.Ahi[NB][ah][awm][aL] = hi4;                                   \
            sm.s.Alo[NB][ah][awm][aL] = lo4;                                   \
        }                                                                      \
        const uint4* wc = wsrc + (size_t)(IT) * 1024;                          \
        _Pragma("unroll")                                                      \
        for (int j = 0; j < 4; ++j) {                                          \
            __builtin_amdgcn_global_load_lds(                                  \
                (const __attribute__((address_space(1))) void*)(wc + j * 64),  \
                (__attribute__((address_space(3))) void*)&sm.s.W[NB][shalf][(wv * 4 + j) * 64], \
                16, 0, 0);                                                     \
        }                                                                      \
    }

    // prologue: stage chunk 0 into buf 0, prefetch A regs for chunk 1
    float4 av0, av1;
    if (doA) { av0 = *(const float4*)(Ag); av1 = *(const float4*)(Ag + 4); }
    STAGE(0, 0);
    if (doA) { av0 = *(const float4*)(Ag + KC); av1 = *(const float4*)(Ag + KC + 4); }
    __syncthreads();

    int b = 0;
    for (int it = 0; it < NCHUNK_H; ++it) {
        // stage next chunk into the other buffer; overlaps compute below
        if (it + 1 < NCHUNK_H) {
            STAGE(b ^ 1, it + 1);
            if (doA && it + 2 < NCHUNK_H) {
                av0 = *(const float4*)(Ag + (it + 2) * KC);
                av1 = *(const float4*)(Ag + (it + 2) * KC + 4);
            }
        }
        // compute current buffer: 10 ds_read_b128 + 12 MFMA 16x16x32
        const bf16x8 ahi = *(const bf16x8*)&sm.s.Ahi[b][whalf][wm][L];
        const bf16x8 alo = *(const bf16x8*)&sm.s.Alo[b][whalf][wm][L];
#pragma unroll
        for (int i = 0; i < 4; ++i) {
            const int nt = wn * 4 + i;
            const bf16x8 whi = *(const bf16x8*)&sm.s.W[b][whalf][nt * 64 + L];
            const bf16x8 wlo = *(const bf16x8*)&sm.s.W[b][whalf][512 + nt * 64 + L];
            acc[i] = __builtin_amdgcn_mfma_f32_16x16x32_bf16(ahi, whi, acc[i], 0, 0, 0);
            acc[i] = __builtin_amdgcn_mfma_f32_16x16x32_bf16(ahi, wlo, acc[i], 0, 0, 0);
            acc[i] = __builtin_amdgcn_mfma_f32_16x16x32_bf16(alo, whi, acc[i], 0, 0, 0);
        }
        __syncthreads();   // vmcnt(0)+lgkmcnt(0) drain lands AFTER compute
        b ^= 1;
    }
#undef STAGE

    // epilogue: C/D layout col(expert)=lane&15, row(token)=(lane>>4)*4+reg
    if (whalf == 0) {
#pragma unroll
        for (int i = 0; i < 4; ++i) {
            const int e = wn * 64 + i * 16 + (L & 15);
            const float bv = bias[e];
#pragma unroll
            for (int r = 0; r < 4; ++r)
                sm.L[wm * 16 + (L >> 4) * 4 + r][e] = acc[i][r] + bv;
        }
    }
    __syncthreads();
    if (whalf == 1) {
#pragma unroll
        for (int i = 0; i < 4; ++i) {
            const int e = wn * 64 + i * 16 + (L & 15);
#pragma unroll
            for (int r = 0; r < 4; ++r)
                sm.L[wm * 16 + (L >> 4) * 4 + r][e] += acc[i][r];
        }
    }
    __syncthreads();

    // top-5 scan (stable strict '>') + gap test + softmax
    if (tid < MT) {
        float v0 = -1e30f, v1 = -1e30f, v2 = -1e30f, v3 = -1e30f, v4 = -1e30f;
        int   i0 = 0, i1 = 0, i2 = 0, i3 = 0, i4 = 0;
        for (int e = 0; e < E_EXP; ++e) {
            const float x = sm.L[tid][e];
            if (x > v4) {
                if (x > v0)      { v4=v3;i4=i3; v3=v2;i3=i2; v2=v1;i2=i1; v1=v0;i1=i0; v0=x;i0=e; }
                else if (x > v1) { v4=v3;i4=i3; v3=v2;i3=i2; v2=v1;i2=i1; v1=x;i1=e; }
                else if (x > v2) { v4=v3;i4=i3; v3=v2;i3=i2; v2=x;i2=e; }
                else if (x > v3) { v4=v3;i4=i3; v3=x;i3=e; }
                else             { v4=x;i4=e; }
            }
        }
        const float g0 = v0 - v1, g1 = v1 - v2, g2 = v2 - v3, g3 = v3 - v4;
        float mg = g0 < g1 ? g0 : g1;
        mg = mg < g2 ? mg : g2;
        mg = mg < g3 ? mg : g3;

        const float e0x = expf(v0 - v0);
        const float e1x = expf(v1 - v0);
        const float e2x = expf(v2 - v0);
        const float e3x = expf(v3 - v0);
        const float s   = e0x + e1x + e2x + e3x;

        const int gt = t_base + tid;
        float* out_scores = out;
        float* out_idx    = out + (size_t)T_TOKENS * TOPK;
        out_scores[gt * 4 + 0] = e0x / s;
        out_scores[gt * 4 + 1] = e1x / s;
        out_scores[gt * 4 + 2] = e2x / s;
        out_scores[gt * 4 + 3] = e3x / s;
        out_idx[gt * 4 + 0] = (float)i0;
        out_idx[gt * 4 + 1] = (float)i1;
        out_idx[gt * 4 + 2] = (float)i2;
        out_idx[gt * 4 + 3] = (float)i3;

        if (mg < EPS_GAP) {
            const int p = atomicAdd(flag_count, 1);
            if (p < T_TOKENS) flag_list[p] = gt;
        }
    }
}

// ---------------------------------------------------------------------------
// Fallback main (ws too small for prep path): round-0 kernel, unchanged.
// ---------------------------------------------------------------------------
__global__ __launch_bounds__(512, 4) void router_main_fb(
    const float* __restrict__ A, const float* __restrict__ W,
    const float* __restrict__ bias, float* __restrict__ out,
    int* __restrict__ flag_count, int* __restrict__ flag_list)
{
    __shared__ __align__(16) uint2 sAhi[2][2][128];
    __shared__ __align__(16) uint2 sAlo[2][2][128];
    __shared__ __align__(16) uint4 sWhi[2][8][64];
    __shared__ __align__(16) uint4 sWlo[2][8][64];
    __shared__ float sL[MT][129];

    const int tid    = threadIdx.x;
    const int t_base = blockIdx.x * MT;
    const int wave  = tid >> 6;
    const int L     = tid & 63;
    const int whalf = wave >> 2;
    const int wm    = wave & 1;
    const int wn    = (wave >> 1) & 1;
    const int shalf = tid >> 8;
    const int tid_h = tid & 255;
    const int at = tid_h >> 3;
    const int ac = tid_h & 7;
    const int a_idx = (at >> 4) * 128 + ((((ac >> 1) << 4) | (at & 15)) << 1) + (ac & 1);
    const float* Ag = A + (size_t)(t_base + at) * H_DIM + shalf * KHALF + ac * 4;
    const int we  = tid_h >> 1;
    const int wq0 = (tid_h & 1) * 2;
    const float* Wg = W + (size_t)we * H_DIM + shalf * KHALF + wq0 * 8;
    const int w_nt = we >> 4;
    const int w_n  = we & 15;

    uint2* sAhiF = &sAhi[shalf][0][0];
    uint2* sAloF = &sAlo[shalf][0][0];

    f32x4 acc[4];
#pragma unroll
    for (int i = 0; i < 4; ++i) { f32x4 z = {0.f, 0.f, 0.f, 0.f}; acc[i] = z; }

    for (int k0 = 0; k0 < KHALF; k0 += KC) {
        const float4 av  = *(const float4*)(Ag + k0);
        const float4 wv0 = *(const float4*)(Wg + k0);
        const float4 wv1 = *(const float4*)(Wg + k0 + 4);
        const float4 wv2 = *(const float4*)(Wg + k0 + 8);
        const float4 wv3 = *(const float4*)(Wg + k0 + 12);

        uint2 ahp, alp;
        split2(av.x, av.y, ahp.x, alp.x);
        split2(av.z, av.w, ahp.y, alp.y);
        uint4 whp0, wlp0, whp1, wlp1;
        split2(wv0.x, wv0.y, whp0.x, wlp0.x);
        split2(wv0.z, wv0.w, whp0.y, wlp0.y);
        split2(wv1.x, wv1.y, whp0.z, wlp0.z);
        split2(wv1.z, wv1.w, whp0.w, wlp0.w);
        split2(wv2.x, wv2.y, whp1.x, wlp1.x);
        split2(wv2.z, wv2.w, whp1.y, wlp1.y);
        split2(wv3.x, wv3.y, whp1.z, wlp1.z);
        split2(wv3.z, wv3.w, whp1.w, wlp1.w);

        __syncthreads();
        sAhiF[a_idx] = ahp;
        sAloF[a_idx] = alp;
        sWhi[shalf][w_nt][((wq0 + 0) << 4) | w_n] = whp0;
        sWhi[shalf][w_nt][((wq0 + 1) << 4) | w_n] = whp1;
        sWlo[shalf][w_nt][((wq0 + 0) << 4) | w_n] = wlp0;
        sWlo[shalf][w_nt][((wq0 + 1) << 4) | w_n] = wlp1;
        __syncthreads();

        const bf16x8 ahi = *(const bf16x8*)&sAhi[whalf][wm][L * 2];
        const bf16x8 alo = *(const bf16x8*)&sAlo[whalf][wm][L * 2];
#pragma unroll
        for (int i = 0; i < 4; ++i) {
            const int nt = wn * 4 + i;
            const bf16x8 whi = *(const bf16x8*)&sWhi[whalf][nt][L];
            const bf16x8 wlo = *(const bf16x8*)&sWlo[whalf][nt][L];
            acc[i] = __builtin_amdgcn_mfma_f32_16x16x32_bf16(ahi, whi, acc[i], 0, 0, 0);
            acc[i] = __builtin_amdgcn_mfma_f32_16x16x32_bf16(ahi, wlo, acc[i], 0, 0, 0);
            acc[i] = __builtin_amdgcn_mfma_f32_16x16x32_bf16(alo, whi, acc[i], 0, 0, 0);
        }
    }

    __syncthreads();
    if (whalf == 0) {
#pragma unroll
        for (int i = 0; i < 4; ++i) {
            const int e = wn * 64 + i * 16 + (L & 15);
            const float b = bias[e];
#pragma unroll
            for (int r = 0; r < 4; ++r)
                sL[wm * 16 + (L >> 4) * 4 + r][e] = acc[i][r] + b;
        }
    }
    __syncthreads();
    if (whalf == 1) {
#pragma unroll
        for (int i = 0; i < 4; ++i) {
            const int e = wn * 64 + i * 16 + (L & 15);
#pragma unroll
            for (int r = 0; r < 4; ++r)
                sL[wm * 16 + (L >> 4) * 4 + r][e] += acc[i][r];
        }
    }
    __syncthreads();

    if (tid < MT) {
        float v0 = -1e30f, v1 = -1e30f, v2 = -1e30f, v3 = -1e30f, v4 = -1e30f;
        int   i0 = 0, i1 = 0, i2 = 0, i3 = 0, i4 = 0;
        for (int e = 0; e < E_EXP; ++e) {
            const float x = sL[tid][e];
            if (x > v4) {
                if (x > v0)      { v4=v3;i4=i3; v3=v2;i3=i2; v2=v1;i2=i1; v1=v0;i1=i0; v0=x;i0=e; }
                else if (x > v1) { v4=v3;i4=i3; v3=v2;i3=i2; v2=v1;i2=i1; v1=x;i1=e; }
                else if (x > v2) { v4=v3;i4=i3; v3=v2;i3=i2; v2=x;i2=e; }
                else if (x > v3) { v4=v3;i4=i3; v3=x;i3=e; }
                else             { v4=x;i4=e; }
            }
        }
        const float g0 = v0 - v1, g1 = v1 - v2, g2 = v2 - v3, g3 = v3 - v4;
        float mg = g0 < g1 ? g0 : g1;
        mg = mg < g2 ? mg : g2;
        mg = mg < g3 ? mg : g3;

        const float e0x = expf(v0 - v0);
        const float e1x = expf(v1 - v0);
        const float e2x = expf(v2 - v0);
        const float e3x = expf(v3 - v0);
        const float s   = e0x + e1x + e2x + e3x;

        const int gt = t_base + tid;
        float* out_scores = out;
        float* out_idx    = out + (size_t)T_TOKENS * TOPK;
        out_scores[gt * 4 + 0] = e0x / s;
        out_scores[gt * 4 + 1] = e1x / s;
        out_scores[gt * 4 + 2] = e2x / s;
        out_scores[gt * 4 + 3] = e3x / s;
        out_idx[gt * 4 + 0] = (float)i0;
        out_idx[gt * 4 + 1] = (float)i1;
        out_idx[gt * 4 + 2] = (float)i2;
        out_idx[gt * 4 + 3] = (float)i3;

        if (mg < EPS_GAP) {
            const int p = atomicAdd(flag_count, 1);
            if (p < T_TOKENS) flag_list[p] = gt;
        }
    }
}

// ---------------------------------------------------------------------------
// Recheck: exact f64 recompute of flagged tokens (unchanged).
// ---------------------------------------------------------------------------
__global__ __launch_bounds__(256) void router_recheck(
    const float* __restrict__ A, const float* __restrict__ W,
    const float* __restrict__ bias, float* __restrict__ out,
    const int* __restrict__ flag_count, const int* __restrict__ flag_list)
{
    __shared__ double sPart[256];
    __shared__ double sLog[E_EXP];

    int count = *flag_count;
    if (count > T_TOKENS) count = T_TOKENS;

    const int tid = threadIdx.x;
    const int e   = tid & (E_EXP - 1);
    const int h   = tid >> 7;          // K half: 0 or 1

    for (int i = blockIdx.x; i < count; i += gridDim.x) {
        const int t = flag_list[i];
        const float* arow = A + (size_t)t * H_DIM + h * KHALF;
        const float* wrow = W + (size_t)e * H_DIM + h * KHALF;

        double s0 = 0.0, s1 = 0.0, s2 = 0.0, s3 = 0.0;
        float4 a[8], w[8];
#pragma unroll
        for (int q = 0; q < 8; ++q) {
            a[q] = *(const float4*)(arow + q * 4);
            w[q] = *(const float4*)(wrow + q * 4);
        }
        for (int it = 0; it < KHALF / 32 - 1; ++it) {
            const float* ap = arow + (it + 1) * 32;
            const float* wp = wrow + (it + 1) * 32;
            float4 na[8], nw[8];
#pragma unroll
            for (int q = 0; q < 8; ++q) {
                na[q] = *(const float4*)(ap + q * 4);
                nw[q] = *(const float4*)(wp + q * 4);
            }
#pragma unroll
            for (int q = 0; q < 8; ++q) {
                s0 += (double)a[q].x * (double)w[q].x;
                s1 += (double)a[q].y * (double)w[q].y;
                s2 += (double)a[q].z * (double)w[q].z;
                s3 += (double)a[q].w * (double)w[q].w;
            }
#pragma unroll
            for (int q = 0; q < 8; ++q) { a[q] = na[q]; w[q] = nw[q]; }
        }
#pragma unroll
        for (int q = 0; q < 8; ++q) {
            s0 += (double)a[q].x * (double)w[q].x;
            s1 += (double)a[q].y * (double)w[q].y;
            s2 += (double)a[q].z * (double)w[q].z;
            s3 += (double)a[q].w * (double)w[q].w;
        }
        sPart[tid] = (s0 + s1) + (s2 + s3);
        __syncthreads();
        if (h == 0) sLog[e] = sPart[e] + sPart[e + 128] + (double)bias[e];
        __syncthreads();

        if (tid == 0) {
            double v0 = -1e300, v1 = -1e300, v2 = -1e300, v3 = -1e300;
            int    i0 = 0, i1 = 0, i2 = 0, i3 = 0;
            for (int q = 0; q < E_EXP; ++q) {
                const double x = sLog[q];
                if (x > v3) {
                    if (x > v0)      { v3=v2;i3=i2; v2=v1;i2=i1; v1=v0;i1=i0; v0=x;i0=q; }
                    else if (x > v1) { v3=v2;i3=i2; v2=v1;i2=i1; v1=x;i1=q; }
                    else if (x > v2) { v3=v2;i3=i2; v2=x;i2=q; }
                    else             { v3=x;i3=q; }
                }
            }
            const double e0x = exp(v0 - v0);
            const double e1x = exp(v1 - v0);
            const double e2x = exp(v2 - v0);
            const double e3x = exp(v3 - v0);
            const double s   = e0x + e1x + e2x + e3x;
            float* out_scores = out;
            float* out_idx    = out + (size_t)T_TOKENS * TOPK;
            out_scores[t * 4 + 0] = (float)(e0x / s);
            out_scores[t * 4 + 1] = (float)(e1x / s);
            out_scores[t * 4 + 2] = (float)(e2x / s);
            out_scores[t * 4 + 3] = (float)(e3x / s);
            out_idx[t * 4 + 0] = (float)i0;
            out_idx[t * 4 + 1] = (float)i1;
            out_idx[t * 4 + 2] = (float)i2;
            out_idx[t * 4 + 3] = (float)i3;
        }
        __syncthreads();
    }
}

extern "C" void kernel_launch(void* const* d_in, const int* in_sizes, int n_in,
                              void* d_out, int out_size, void* d_ws, size_t ws_size,
                              hipStream_t stream) {
    const float* A    = (const float*)d_in[0];
    const float* W    = (const float*)d_in[1];
    const float* bias = (const float*)d_in[2];
    float* out = (float*)d_out;

    if (ws_size >= (size_t)WS_NEED) {
        int*  flag_count = (int*)d_ws;
        int*  flag_list  = (int*)((char*)d_ws + WS_FLOFF);
        uint4* wsW       = (uint4*)((char*)d_ws + WS_WOFF);
        hipMemsetAsync(flag_count, 0, sizeof(int), stream);
        prep_w<<<dim3((NCHUNK * 512) / 256), dim3(256), 0, stream>>>(W, wsW);
        router_main<<<dim3(T_TOKENS / MT), dim3(512), 0, stream>>>(A, wsW, bias, out,
                                                                   flag_count, flag_list);
        router_recheck<<<dim3(512), dim3(256), 0, stream>>>(A, W, bias, out,
                                                            flag_count, flag_list);
    } else {
        int* flag_count = (int*)d_ws;
        int* flag_list  = (int*)d_ws + 1;
        hipMemsetAsync(flag_count, 0, sizeof(int), stream);
        router_main_fb<<<dim3(T_TOKENS / MT), dim3(512), 0, stream>>>(A, W, bias, out,
                                                                      flag_count, flag_list);
        router_recheck<<<dim3(512), dim3(256), 0, stream>>>(A, W, bias, out,
                                                            flag_count, flag_list);
    }
}

// Round 3
// 374.513 us; speedup vs baseline: 1.2900x; 1.0138x over previous
//
#include <hip/hip_runtime.h>
#include <hip/hip_bf16.h>
#include <math.h>

#define T_TOKENS 16384
#define H_DIM    2880
#define KHALF    1440      // H_DIM/2, per in-block K-split half
#define E_EXP    128
#define TOPK     4
#define MT       32        // fb kernel tokens per block
#define MTM      64        // main kernel tokens per block
#define KC       32        // K chunk per iteration
#define NCHUNK   (H_DIM / KC)          // 90
#define NCHUNK_H (KHALF / KC)          // 45
#define EPS_GAP  5e-4f

// d_ws layout (prep path):
//   [0..63]                : flag_count (int at offset 0) + pad
//   [64 .. 64+1.44MB)      : W frags, [chunk kc][hi:512 | lo:512 uint4]
//   [then]                 : flag_list (T_TOKENS ints)
#define WS_WOFF   64
#define WS_WBYTES (NCHUNK * 1024 * 16)
#define WS_FLOFF  (WS_WOFF + WS_WBYTES)
#define WS_NEED   (WS_FLOFF + T_TOKENS * 4)

typedef __bf16 bf16x8 __attribute__((ext_vector_type(8)));
typedef float  f32x4  __attribute__((ext_vector_type(4)));

// packed RNE split: (a,b) -> hi word [b_hi|a_hi], lo word [b_lo|a_lo]
__device__ __forceinline__ void split2(float a, float b,
                                       unsigned int& hi, unsigned int& lo) {
    float2 p; p.x = a; p.y = b;
    __hip_bfloat162 h = __float22bfloat162_rn(p);
    unsigned int hu; __builtin_memcpy(&hu, &h, 4);
    float2 r;
    r.x = a - __uint_as_float((hu & 0xffffu) << 16);
    r.y = b - __uint_as_float(hu & 0xffff0000u);
    __hip_bfloat162 l = __float22bfloat162_rn(r);
    unsigned int lu; __builtin_memcpy(&lu, &l, 4);
    hi = hu; lo = lu;
}

// ---------------------------------------------------------------------------
// Prep: split W into MFMA-fragment-ordered bf16 hi/lo (unchanged layout).
// Frag (kc, nt, L): e = nt*16 + (L&15), k = kc*32 + (L>>4)*8 .. +7.
// ---------------------------------------------------------------------------
__global__ __launch_bounds__(256) void prep_w(const float* __restrict__ W,
                                              uint4* __restrict__ wsW) {
    const int f   = blockIdx.x * 256 + threadIdx.x;   // 0 .. 46079
    const int kc  = f >> 9;
    const int rem = f & 511;
    const int nt  = rem >> 6;
    const int L   = rem & 63;
    const int e   = nt * 16 + (L & 15);
    const int k   = kc * KC + (L >> 4) * 8;
    const float* p = W + (size_t)e * H_DIM + k;
    const float4 x0 = *(const float4*)p;
    const float4 x1 = *(const float4*)(p + 4);
    uint4 hi, lo;
    split2(x0.x, x0.y, hi.x, lo.x);
    split2(x0.z, x0.w, hi.y, lo.y);
    split2(x1.x, x1.y, hi.z, lo.z);
    split2(x1.z, x1.w, hi.w, lo.w);
    wsW[(size_t)kc * 1024 + nt * 64 + L]       = hi;
    wsW[(size_t)kc * 1024 + 512 + nt * 64 + L] = lo;
}

// ---------------------------------------------------------------------------
// Main: MT=64, 1024 threads (16 waves), 1 block/CU, grid 256.
// Same 16x16x32 bf16x3 compute, in-block split-K over 2 halves.
// Wave (whalf, wmg, wng): 2 m-tiles (wmg*2..+1) x 2 n-tiles (wng*2..+1):
// W-read dup 2, A-read dup 4 -> 44 LDS-B/token.k (vs 58.6 at MT=32),
// and W L2 traffic halved (one block per CU stages W once per iter).
// Stage-ahead single-barrier double-buffer as round 2.
// LDS: W dbuf 64 KB + A dbuf 32 KB (logits overlaid) = 96 KB.
// ---------------------------------------------------------------------------
__global__ __launch_bounds__(1024, 4) void router_main(
    const float* __restrict__ A, const uint4* __restrict__ wsW,
    const float* __restrict__ bias, float* __restrict__ out,
    int* __restrict__ flag_count, int* __restrict__ flag_list)
{
    union SMem {
        struct {
            uint4 W  [2][2][1024];    // [buf][half][hi:512|lo:512 frags] 64 KB
            uint4 Ahi[2][2][4][64];   // [buf][half][mt][lane]            16 KB
            uint4 Alo[2][2][4][64];   //                                  16 KB
        } s;
        float L[MTM][129];            // logits (epilogue only)           33 KB
    };
    __shared__ SMem sm;

    const int tid    = threadIdx.x;
    const int t_base = blockIdx.x * MTM;

    const int wave  = tid >> 6;
    const int L     = tid & 63;
    const int whalf = wave >> 3;        // K half this wave computes
    const int wmg   = (wave >> 2) & 1;  // m-group: m-tiles wmg*2, wmg*2+1
    const int wng   = wave & 3;         // n-group: n-tiles wng*2, wng*2+1

    // W staging: wave stages 2 frag-chunks of its half's K-chunk
    const int shalf = whalf;
    const int wv    = wave & 7;
    const uint4* wsrc = wsW + (size_t)(shalf * NCHUNK_H) * 1024 + (wv * 2) * 64 + L;

    // A staging (threads 0..511): token at = tid>>3, octet ac = tid&7
    // (ah = half, akq = k-octet). 32B load, 4x split2, 2 linear uint4 writes
    // at frag slot (akq<<4)|(at&15) -- same measured-conflict-free pattern
    // as round 2, widened to 4 m-tiles.
    const bool doA = tid < 512;
    const int at   = (tid >> 3) & 63;
    const int ac   = tid & 7;
    const int ah   = ac >> 2;
    const int akq  = ac & 3;
    const int awm  = at >> 4;           // m-tile 0..3
    const int aL   = (akq << 4) | (at & 15);
    const float* Ag = A + (size_t)(t_base + at) * H_DIM + ah * KHALF + akq * 8;

    f32x4 acc[2][2];
#pragma unroll
    for (int m = 0; m < 2; ++m)
#pragma unroll
        for (int n = 0; n < 2; ++n) { f32x4 z = {0.f, 0.f, 0.f, 0.f}; acc[m][n] = z; }

#define STAGE(NB, IT)                                                          \
    {                                                                          \
        if (doA) {                                                             \
            uint4 hi4, lo4;                                                    \
            split2(av0.x, av0.y, hi4.x, lo4.x);                                \
            split2(av0.z, av0.w, hi4.y, lo4.y);                                \
            split2(av1.x, av1.y, hi4.z, lo4.z);                                \
            split2(av1.z, av1.w, hi4.w, lo4.w);                                \
            sm.s.Ahi[NB][ah][awm][aL] = hi4;                                   \
            sm.s.Alo[NB][ah][awm][aL] = lo4;                                   \
        }                                                                      \
        const uint4* wc = wsrc + (size_t)(IT) * 1024;                          \
        _Pragma("unroll")                                                      \
        for (int j = 0; j < 2; ++j) {                                          \
            __builtin_amdgcn_global_load_lds(                                  \
                (const __attribute__((address_space(1))) void*)(wc + j * 64),  \
                (__attribute__((address_space(3))) void*)&sm.s.W[NB][shalf][(wv * 2 + j) * 64], \
                16, 0, 0);                                                     \
        }                                                                      \
    }

    // prologue: stage chunk 0 into buf 0, prefetch A regs for chunk 1
    float4 av0, av1;
    if (doA) { av0 = *(const float4*)(Ag); av1 = *(const float4*)(Ag + 4); }
    STAGE(0, 0);
    if (doA) { av0 = *(const float4*)(Ag + KC); av1 = *(const float4*)(Ag + KC + 4); }
    __syncthreads();

    int b = 0;
    for (int it = 0; it < NCHUNK_H; ++it) {
        // stage next chunk into the other buffer; overlaps compute below
        if (it + 1 < NCHUNK_H) {
            STAGE(b ^ 1, it + 1);
            if (doA && it + 2 < NCHUNK_H) {
                av0 = *(const float4*)(Ag + (it + 2) * KC);
                av1 = *(const float4*)(Ag + (it + 2) * KC + 4);
            }
        }
        // compute current buffer: 8 ds_read_b128 + 12 MFMA 16x16x32
        const bf16x8 ah0 = *(const bf16x8*)&sm.s.Ahi[b][whalf][wmg * 2 + 0][L];
        const bf16x8 al0 = *(const bf16x8*)&sm.s.Alo[b][whalf][wmg * 2 + 0][L];
        const bf16x8 ah1 = *(const bf16x8*)&sm.s.Ahi[b][whalf][wmg * 2 + 1][L];
        const bf16x8 al1 = *(const bf16x8*)&sm.s.Alo[b][whalf][wmg * 2 + 1][L];
#pragma unroll
        for (int n = 0; n < 2; ++n) {
            const int nt = wng * 2 + n;
            const bf16x8 whi = *(const bf16x8*)&sm.s.W[b][whalf][nt * 64 + L];
            const bf16x8 wlo = *(const bf16x8*)&sm.s.W[b][whalf][512 + nt * 64 + L];
            acc[0][n] = __builtin_amdgcn_mfma_f32_16x16x32_bf16(ah0, whi, acc[0][n], 0, 0, 0);
            acc[0][n] = __builtin_amdgcn_mfma_f32_16x16x32_bf16(ah0, wlo, acc[0][n], 0, 0, 0);
            acc[0][n] = __builtin_amdgcn_mfma_f32_16x16x32_bf16(al0, whi, acc[0][n], 0, 0, 0);
            acc[1][n] = __builtin_amdgcn_mfma_f32_16x16x32_bf16(ah1, whi, acc[1][n], 0, 0, 0);
            acc[1][n] = __builtin_amdgcn_mfma_f32_16x16x32_bf16(ah1, wlo, acc[1][n], 0, 0, 0);
            acc[1][n] = __builtin_amdgcn_mfma_f32_16x16x32_bf16(al1, whi, acc[1][n], 0, 0, 0);
        }
        __syncthreads();   // vmcnt(0)+lgkmcnt(0) drain lands AFTER compute
        b ^= 1;
    }
#undef STAGE

    // epilogue: C/D layout col(expert)=lane&15, row(token)=(lane>>4)*4+reg
    if (whalf == 0) {
#pragma unroll
        for (int m = 0; m < 2; ++m)
#pragma unroll
            for (int n = 0; n < 2; ++n) {
                const int e = (wng * 2 + n) * 16 + (L & 15);
                const float bv = bias[e];
#pragma unroll
                for (int r = 0; r < 4; ++r)
                    sm.L[(wmg * 2 + m) * 16 + (L >> 4) * 4 + r][e] = acc[m][n][r] + bv;
            }
    }
    __syncthreads();
    if (whalf == 1) {
#pragma unroll
        for (int m = 0; m < 2; ++m)
#pragma unroll
            for (int n = 0; n < 2; ++n) {
                const int e = (wng * 2 + n) * 16 + (L & 15);
#pragma unroll
                for (int r = 0; r < 4; ++r)
                    sm.L[(wmg * 2 + m) * 16 + (L >> 4) * 4 + r][e] += acc[m][n][r];
            }
    }
    __syncthreads();

    // top-5 scan (stable strict '>') + gap test + softmax
    if (tid < MTM) {
        float v0 = -1e30f, v1 = -1e30f, v2 = -1e30f, v3 = -1e30f, v4 = -1e30f;
        int   i0 = 0, i1 = 0, i2 = 0, i3 = 0, i4 = 0;
        for (int e = 0; e < E_EXP; ++e) {
            const float x = sm.L[tid][e];
            if (x > v4) {
                if (x > v0)      { v4=v3;i4=i3; v3=v2;i3=i2; v2=v1;i2=i1; v1=v0;i1=i0; v0=x;i0=e; }
                else if (x > v1) { v4=v3;i4=i3; v3=v2;i3=i2; v2=v1;i2=i1; v1=x;i1=e; }
                else if (x > v2) { v4=v3;i4=i3; v3=v2;i3=i2; v2=x;i2=e; }
                else if (x > v3) { v4=v3;i4=i3; v3=x;i3=e; }
                else             { v4=x;i4=e; }
            }
        }
        const float g0 = v0 - v1, g1 = v1 - v2, g2 = v2 - v3, g3 = v3 - v4;
        float mg = g0 < g1 ? g0 : g1;
        mg = mg < g2 ? mg : g2;
        mg = mg < g3 ? mg : g3;

        const float e0x = expf(v0 - v0);
        const float e1x = expf(v1 - v0);
        const float e2x = expf(v2 - v0);
        const float e3x = expf(v3 - v0);
        const float s   = e0x + e1x + e2x + e3x;

        const int gt = t_base + tid;
        float* out_scores = out;
        float* out_idx    = out + (size_t)T_TOKENS * TOPK;
        out_scores[gt * 4 + 0] = e0x / s;
        out_scores[gt * 4 + 1] = e1x / s;
        out_scores[gt * 4 + 2] = e2x / s;
        out_scores[gt * 4 + 3] = e3x / s;
        out_idx[gt * 4 + 0] = (float)i0;
        out_idx[gt * 4 + 1] = (float)i1;
        out_idx[gt * 4 + 2] = (float)i2;
        out_idx[gt * 4 + 3] = (float)i3;

        if (mg < EPS_GAP) {
            const int p = atomicAdd(flag_count, 1);
            if (p < T_TOKENS) flag_list[p] = gt;
        }
    }
}

// ---------------------------------------------------------------------------
// Fallback main (ws too small for prep path): round-0 kernel, unchanged.
// ---------------------------------------------------------------------------
__global__ __launch_bounds__(512, 4) void router_main_fb(
    const float* __restrict__ A, const float* __restrict__ W,
    const float* __restrict__ bias, float* __restrict__ out,
    int* __restrict__ flag_count, int* __restrict__ flag_list)
{
    __shared__ __align__(16) uint2 sAhi[2][2][128];
    __shared__ __align__(16) uint2 sAlo[2][2][128];
    __shared__ __align__(16) uint4 sWhi[2][8][64];
    __shared__ __align__(16) uint4 sWlo[2][8][64];
    __shared__ float sL[MT][129];

    const int tid    = threadIdx.x;
    const int t_base = blockIdx.x * MT;
    const int wave  = tid >> 6;
    const int L     = tid & 63;
    const int whalf = wave >> 2;
    const int wm    = wave & 1;
    const int wn    = (wave >> 1) & 1;
    const int shalf = tid >> 8;
    const int tid_h = tid & 255;
    const int at = tid_h >> 3;
    const int ac = tid_h & 7;
    const int a_idx = (at >> 4) * 128 + ((((ac >> 1) << 4) | (at & 15)) << 1) + (ac & 1);
    const float* Ag = A + (size_t)(t_base + at) * H_DIM + shalf * KHALF + ac * 4;
    const int we  = tid_h >> 1;
    const int wq0 = (tid_h & 1) * 2;
    const float* Wg = W + (size_t)we * H_DIM + shalf * KHALF + wq0 * 8;
    const int w_nt = we >> 4;
    const int w_n  = we & 15;

    uint2* sAhiF = &sAhi[shalf][0][0];
    uint2* sAloF = &sAlo[shalf][0][0];

    f32x4 acc[4];
#pragma unroll
    for (int i = 0; i < 4; ++i) { f32x4 z = {0.f, 0.f, 0.f, 0.f}; acc[i] = z; }

    for (int k0 = 0; k0 < KHALF; k0 += KC) {
        const float4 av  = *(const float4*)(Ag + k0);
        const float4 wv0 = *(const float4*)(Wg + k0);
        const float4 wv1 = *(const float4*)(Wg + k0 + 4);
        const float4 wv2 = *(const float4*)(Wg + k0 + 8);
        const float4 wv3 = *(const float4*)(Wg + k0 + 12);

        uint2 ahp, alp;
        split2(av.x, av.y, ahp.x, alp.x);
        split2(av.z, av.w, ahp.y, alp.y);
        uint4 whp0, wlp0, whp1, wlp1;
        split2(wv0.x, wv0.y, whp0.x, wlp0.x);
        split2(wv0.z, wv0.w, whp0.y, wlp0.y);
        split2(wv1.x, wv1.y, whp0.z, wlp0.z);
        split2(wv1.z, wv1.w, whp0.w, wlp0.w);
        split2(wv2.x, wv2.y, whp1.x, wlp1.x);
        split2(wv2.z, wv2.w, whp1.y, wlp1.y);
        split2(wv3.x, wv3.y, whp1.z, wlp1.z);
        split2(wv3.z, wv3.w, whp1.w, wlp1.w);

        __syncthreads();
        sAhiF[a_idx] = ahp;
        sAloF[a_idx] = alp;
        sWhi[shalf][w_nt][((wq0 + 0) << 4) | w_n] = whp0;
        sWhi[shalf][w_nt][((wq0 + 1) << 4) | w_n] = whp1;
        sWlo[shalf][w_nt][((wq0 + 0) << 4) | w_n] = wlp0;
        sWlo[shalf][w_nt][((wq0 + 1) << 4) | w_n] = wlp1;
        __syncthreads();

        const bf16x8 ahi = *(const bf16x8*)&sAhi[whalf][wm][L * 2];
        const bf16x8 alo = *(const bf16x8*)&sAlo[whalf][wm][L * 2];
#pragma unroll
        for (int i = 0; i < 4; ++i) {
            const int nt = wn * 4 + i;
            const bf16x8 whi = *(const bf16x8*)&sWhi[whalf][nt][L];
            const bf16x8 wlo = *(const bf16x8*)&sWlo[whalf][nt][L];
            acc[i] = __builtin_amdgcn_mfma_f32_16x16x32_bf16(ahi, whi, acc[i], 0, 0, 0);
            acc[i] = __builtin_amdgcn_mfma_f32_16x16x32_bf16(ahi, wlo, acc[i], 0, 0, 0);
            acc[i] = __builtin_amdgcn_mfma_f32_16x16x32_bf16(alo, whi, acc[i], 0, 0, 0);
        }
    }

    __syncthreads();
    if (whalf == 0) {
#pragma unroll
        for (int i = 0; i < 4; ++i) {
            const int e = wn * 64 + i * 16 + (L & 15);
            const float b = bias[e];
#pragma unroll
            for (int r = 0; r < 4; ++r)
                sL[wm * 16 + (L >> 4) * 4 + r][e] = acc[i][r] + b;
        }
    }
    __syncthreads();
    if (whalf == 1) {
#pragma unroll
        for (int i = 0; i < 4; ++i) {
            const int e = wn * 64 + i * 16 + (L & 15);
#pragma unroll
            for (int r = 0; r < 4; ++r)
                sL[wm * 16 + (L >> 4) * 4 + r][e] += acc[i][r];
        }
    }
    __syncthreads();

    if (tid < MT) {
        float v0 = -1e30f, v1 = -1e30f, v2 = -1e30f, v3 = -1e30f, v4 = -1e30f;
        int   i0 = 0, i1 = 0, i2 = 0, i3 = 0, i4 = 0;
        for (int e = 0; e < E_EXP; ++e) {
            const float x = sL[tid][e];
            if (x > v4) {
                if (x > v0)      { v4=v3;i4=i3; v3=v2;i3=i2; v2=v1;i2=i1; v1=v0;i1=i0; v0=x;i0=e; }
                else if (x > v1) { v4=v3;i4=i3; v3=v2;i3=i2; v2=v1;i2=i1; v1=x;i1=e; }
                else if (x > v2) { v4=v3;i4=i3; v3=v2;i3=i2; v2=x;i2=e; }
                else if (x > v3) { v4=v3;i4=i3; v3=x;i3=e; }
                else             { v4=x;i4=e; }
            }
        }
        const float g0 = v0 - v1, g1 = v1 - v2, g2 = v2 - v3, g3 = v3 - v4;
        float mg = g0 < g1 ? g0 : g1;
        mg = mg < g2 ? mg : g2;
        mg = mg < g3 ? mg : g3;

        const float e0x = expf(v0 - v0);
        const float e1x = expf(v1 - v0);
        const float e2x = expf(v2 - v0);
        const float e3x = expf(v3 - v0);
        const float s   = e0x + e1x + e2x + e3x;

        const int gt = t_base + tid;
        float* out_scores = out;
        float* out_idx    = out + (size_t)T_TOKENS * TOPK;
        out_scores[gt * 4 + 0] = e0x / s;
        out_scores[gt * 4 + 1] = e1x / s;
        out_scores[gt * 4 + 2] = e2x / s;
        out_scores[gt * 4 + 3] = e3x / s;
        out_idx[gt * 4 + 0] = (float)i0;
        out_idx[gt * 4 + 1] = (float)i1;
        out_idx[gt * 4 + 2] = (float)i2;
        out_idx[gt * 4 + 3] = (float)i3;

        if (mg < EPS_GAP) {
            const int p = atomicAdd(flag_count, 1);
            if (p < T_TOKENS) flag_list[p] = gt;
        }
    }
}

// ---------------------------------------------------------------------------
// Recheck: exact f64 recompute of flagged tokens (unchanged).
// ---------------------------------------------------------------------------
__global__ __launch_bounds__(256) void router_recheck(
    const float* __restrict__ A, const float* __restrict__ W,
    const float* __restrict__ bias, float* __restrict__ out,
    const int* __restrict__ flag_count, const int* __restrict__ flag_list)
{
    __shared__ double sPart[256];
    __shared__ double sLog[E_EXP];

    int count = *flag_count;
    if (count > T_TOKENS) count = T_TOKENS;

    const int tid = threadIdx.x;
    const int e   = tid & (E_EXP - 1);
    const int h   = tid >> 7;          // K half: 0 or 1

    for (int i = blockIdx.x; i < count; i += gridDim.x) {
        const int t = flag_list[i];
        const float* arow = A + (size_t)t * H_DIM + h * KHALF;
        const float* wrow = W + (size_t)e * H_DIM + h * KHALF;

        double s0 = 0.0, s1 = 0.0, s2 = 0.0, s3 = 0.0;
        float4 a[8], w[8];
#pragma unroll
        for (int q = 0; q < 8; ++q) {
            a[q] = *(const float4*)(arow + q * 4);
            w[q] = *(const float4*)(wrow + q * 4);
        }
        for (int it = 0; it < KHALF / 32 - 1; ++it) {
            const float* ap = arow + (it + 1) * 32;
            const float* wp = wrow + (it + 1) * 32;
            float4 na[8], nw[8];
#pragma unroll
            for (int q = 0; q < 8; ++q) {
                na[q] = *(const float4*)(ap + q * 4);
                nw[q] = *(const float4*)(wp + q * 4);
            }
#pragma unroll
            for (int q = 0; q < 8; ++q) {
                s0 += (double)a[q].x * (double)w[q].x;
                s1 += (double)a[q].y * (double)w[q].y;
                s2 += (double)a[q].z * (double)w[q].z;
                s3 += (double)a[q].w * (double)w[q].w;
            }
#pragma unroll
            for (int q = 0; q < 8; ++q) { a[q] = na[q]; w[q] = nw[q]; }
        }
#pragma unroll
        for (int q = 0; q < 8; ++q) {
            s0 += (double)a[q].x * (double)w[q].x;
            s1 += (double)a[q].y * (double)w[q].y;
            s2 += (double)a[q].z * (double)w[q].z;
            s3 += (double)a[q].w * (double)w[q].w;
        }
        sPart[tid] = (s0 + s1) + (s2 + s3);
        __syncthreads();
        if (h == 0) sLog[e] = sPart[e] + sPart[e + 128] + (double)bias[e];
        __syncthreads();

        if (tid == 0) {
            double v0 = -1e300, v1 = -1e300, v2 = -1e300, v3 = -1e300;
            int    i0 = 0, i1 = 0, i2 = 0, i3 = 0;
            for (int q = 0; q < E_EXP; ++q) {
                const double x = sLog[q];
                if (x > v3) {
                    if (x > v0)      { v3=v2;i3=i2; v2=v1;i2=i1; v1=v0;i1=i0; v0=x;i0=q; }
                    else if (x > v1) { v3=v2;i3=i2; v2=v1;i2=i1; v1=x;i1=q; }
                    else if (x > v2) { v3=v2;i3=i2; v2=x;i2=q; }
                    else             { v3=x;i3=q; }
                }
            }
            const double e0x = exp(v0 - v0);
            const double e1x = exp(v1 - v0);
            const double e2x = exp(v2 - v0);
            const double e3x = exp(v3 - v0);
            const double s   = e0x + e1x + e2x + e3x;
            float* out_scores = out;
            float* out_idx    = out + (size_t)T_TOKENS * TOPK;
            out_scores[t * 4 + 0] = (float)(e0x / s);
            out_scores[t * 4 + 1] = (float)(e1x / s);
            out_scores[t * 4 + 2] = (float)(e2x / s);
            out_scores[t * 4 + 3] = (float)(e3x / s);
            out_idx[t * 4 + 0] = (float)i0;
            out_idx[t * 4 + 1] = (float)i1;
            out_idx[t * 4 + 2] = (float)i2;
            out_idx[t * 4 + 3] = (float)i3;
        }
        __syncthreads();
    }
}

extern "C" void kernel_launch(void* const* d_in, const int* in_sizes, int n_in,
                              void* d_out, int out_size, void* d_ws, size_t ws_size,
                              hipStream_t stream) {
    const float* A    = (const float*)d_in[0];
    const float* W    = (const float*)d_in[1];
    const float* bias = (const float*)d_in[2];
    float* out = (float*)d_out;

    if (ws_size >= (size_t)WS_NEED) {
        int*  flag_count = (int*)d_ws;
        int*  flag_list  = (int*)((char*)d_ws + WS_FLOFF);
        uint4* wsW       = (uint4*)((char*)d_ws + WS_WOFF);
        hipMemsetAsync(flag_count, 0, sizeof(int), stream);
        prep_w<<<dim3((NCHUNK * 512) / 256), dim3(256), 0, stream>>>(W, wsW);
        router_main<<<dim3(T_TOKENS / MTM), dim3(1024), 0, stream>>>(A, wsW, bias, out,
                                                                     flag_count, flag_list);
        router_recheck<<<dim3(512), dim3(256), 0, stream>>>(A, W, bias, out,
                                                            flag_count, flag_list);
    } else {
        int* flag_count = (int*)d_ws;
        int* flag_list  = (int*)d_ws + 1;
        hipMemsetAsync(flag_count, 0, sizeof(int), stream);
        router_main_fb<<<dim3(T_TOKENS / MT), dim3(512), 0, stream>>>(A, W, bias, out,
                                                                      flag_count, flag_list);
        router_recheck<<<dim3(512), dim3(256), 0, stream>>>(A, W, bias, out,
                                                            flag_count, flag_list);
    }
}

// Round 4
// 354.869 us; speedup vs baseline: 1.3614x; 1.0554x over previous
//
#include <hip/hip_runtime.h>
#include <hip/hip_bf16.h>
#include <math.h>

#define T_TOKENS 16384
#define H_DIM    2880
#define KHALF    1440      // H_DIM/2, per in-block K-split half
#define E_EXP    128
#define TOPK     4
#define MT       32        // fb kernel tokens per block
#define MTM      64        // main kernel tokens per block
#define KC       32        // K chunk per iteration
#define NCHUNK   (H_DIM / KC)          // 90
#define NCHUNK_H (KHALF / KC)          // 45
#define EPS_GAP  5e-4f

// d_ws layout (prep path):
//   [0..63]                   : flag_count (int at offset 0) + pad
//   [64 .. 64+1.44MB)         : W frags, [chunk kc][hi:512 | lo:512 uint4]
//   [WS_FLOFF .. +64KB)       : flag_list (T_TOKENS ints)
//   [WS_CAOFF .. +128KB)      : cand_list (T_TOKENS uint2: 8 expert bytes)
#define WS_WOFF   64
#define WS_WBYTES (NCHUNK * 1024 * 16)
#define WS_FLOFF  (WS_WOFF + WS_WBYTES)
#define WS_CAOFF  (WS_FLOFF + T_TOKENS * 4)
#define WS_NEED   (WS_CAOFF + T_TOKENS * 8)

typedef __bf16 bf16x8 __attribute__((ext_vector_type(8)));
typedef float  f32x4  __attribute__((ext_vector_type(4)));

// packed RNE split: (a,b) -> hi word [b_hi|a_hi], lo word [b_lo|a_lo]
__device__ __forceinline__ void split2(float a, float b,
                                       unsigned int& hi, unsigned int& lo) {
    float2 p; p.x = a; p.y = b;
    __hip_bfloat162 h = __float22bfloat162_rn(p);
    unsigned int hu; __builtin_memcpy(&hu, &h, 4);
    float2 r;
    r.x = a - __uint_as_float((hu & 0xffffu) << 16);
    r.y = b - __uint_as_float(hu & 0xffff0000u);
    __hip_bfloat162 l = __float22bfloat162_rn(r);
    unsigned int lu; __builtin_memcpy(&lu, &l, 4);
    hi = hu; lo = lu;
}

// ---------------------------------------------------------------------------
// Prep: split W into MFMA-fragment-ordered bf16 hi/lo (unchanged layout).
// Frag (kc, nt, L): e = nt*16 + (L&15), k = kc*32 + (L>>4)*8 .. +7.
// ---------------------------------------------------------------------------
__global__ __launch_bounds__(256) void prep_w(const float* __restrict__ W,
                                              uint4* __restrict__ wsW) {
    const int f   = blockIdx.x * 256 + threadIdx.x;   // 0 .. 46079
    const int kc  = f >> 9;
    const int rem = f & 511;
    const int nt  = rem >> 6;
    const int L   = rem & 63;
    const int e   = nt * 16 + (L & 15);
    const int k   = kc * KC + (L >> 4) * 8;
    const float* p = W + (size_t)e * H_DIM + k;
    const float4 x0 = *(const float4*)p;
    const float4 x1 = *(const float4*)(p + 4);
    uint4 hi, lo;
    split2(x0.x, x0.y, hi.x, lo.x);
    split2(x0.z, x0.w, hi.y, lo.y);
    split2(x1.x, x1.y, hi.z, lo.z);
    split2(x1.z, x1.w, hi.w, lo.w);
    wsW[(size_t)kc * 1024 + nt * 64 + L]       = hi;
    wsW[(size_t)kc * 1024 + 512 + nt * 64 + L] = lo;
}

// ---------------------------------------------------------------------------
// Main: MT=64, 1024 threads (16 waves), grid 256 (1 block/CU).
// 16x16x32 bf16x3, in-block split-K over 2 halves, stage-ahead single-barrier
// double-buffer. A-staging remapped so each wave writes ONE contiguous 1KB
// run (conflict-free b128): wave w (0..7): ah=w&1, awm=w>>1; lane l:
// akq=l>>4, t16=l&15, at=awm*16+t16, slot aL=l.
// Flag path now also records <=8 candidate experts per flagged token.
// ---------------------------------------------------------------------------
__global__ __launch_bounds__(1024, 4) void router_main(
    const float* __restrict__ A, const uint4* __restrict__ wsW,
    const float* __restrict__ bias, float* __restrict__ out,
    int* __restrict__ flag_count, int* __restrict__ flag_list,
    uint2* __restrict__ cand_list)
{
    union SMem {
        struct {
            uint4 W  [2][2][1024];    // [buf][half][hi:512|lo:512 frags] 64 KB
            uint4 Ahi[2][2][4][64];   // [buf][half][mt][lane]            16 KB
            uint4 Alo[2][2][4][64];   //                                  16 KB
        } s;
        float L[MTM][129];            // logits (epilogue only)           33 KB
    };
    __shared__ SMem sm;

    const int tid    = threadIdx.x;
    const int t_base = blockIdx.x * MTM;

    const int wave  = tid >> 6;
    const int L     = tid & 63;
    const int whalf = wave >> 3;        // K half this wave computes
    const int wmg   = (wave >> 2) & 1;  // m-group: m-tiles wmg*2, wmg*2+1
    const int wng   = wave & 3;         // n-group: n-tiles wng*2, wng*2+1

    // W staging: wave stages 2 frag-chunks of its half's K-chunk
    const int shalf = whalf;
    const int wv    = wave & 7;
    const uint4* wsrc = wsW + (size_t)(shalf * NCHUNK_H) * 1024 + (wv * 2) * 64 + L;

    // A staging (waves 0..7): conflict-free contiguous per-wave writes.
    const bool doA = tid < 512;
    const int ah   = wave & 1;          // K half staged
    const int awm  = (wave >> 1) & 3;   // m-tile staged
    const int akq  = L >> 4;            // k-octet
    const int t16  = L & 15;
    const int at   = awm * 16 + t16;    // token within block
    const float* Ag = A + (size_t)(t_base + at) * H_DIM + ah * KHALF + akq * 8;

    f32x4 acc[2][2];
#pragma unroll
    for (int m = 0; m < 2; ++m)
#pragma unroll
        for (int n = 0; n < 2; ++n) { f32x4 z = {0.f, 0.f, 0.f, 0.f}; acc[m][n] = z; }

#define STAGE(NB, IT)                                                          \
    {                                                                          \
        if (doA) {                                                             \
            uint4 hi4, lo4;                                                    \
            split2(av0.x, av0.y, hi4.x, lo4.x);                                \
            split2(av0.z, av0.w, hi4.y, lo4.y);                                \
            split2(av1.x, av1.y, hi4.z, lo4.z);                                \
            split2(av1.z, av1.w, hi4.w, lo4.w);                                \
            sm.s.Ahi[NB][ah][awm][L] = hi4;                                    \
            sm.s.Alo[NB][ah][awm][L] = lo4;                                    \
        }                                                                      \
        const uint4* wc = wsrc + (size_t)(IT) * 1024;                          \
        _Pragma("unroll")                                                      \
        for (int j = 0; j < 2; ++j) {                                          \
            __builtin_amdgcn_global_load_lds(                                  \
                (const __attribute__((address_space(1))) void*)(wc + j * 64),  \
                (__attribute__((address_space(3))) void*)&sm.s.W[NB][shalf][(wv * 2 + j) * 64], \
                16, 0, 0);                                                     \
        }                                                                      \
    }

    // prologue: stage chunk 0 into buf 0, prefetch A regs for chunk 1
    float4 av0, av1;
    if (doA) { av0 = *(const float4*)(Ag); av1 = *(const float4*)(Ag + 4); }
    STAGE(0, 0);
    if (doA) { av0 = *(const float4*)(Ag + KC); av1 = *(const float4*)(Ag + KC + 4); }
    __syncthreads();

    int b = 0;
    for (int it = 0; it < NCHUNK_H; ++it) {
        // stage next chunk into the other buffer; overlaps compute below
        if (it + 1 < NCHUNK_H) {
            STAGE(b ^ 1, it + 1);
            if (doA && it + 2 < NCHUNK_H) {
                av0 = *(const float4*)(Ag + (it + 2) * KC);
                av1 = *(const float4*)(Ag + (it + 2) * KC + 4);
            }
        }
        // compute current buffer: 8 ds_read_b128 + 12 MFMA 16x16x32
        const bf16x8 ah0 = *(const bf16x8*)&sm.s.Ahi[b][whalf][wmg * 2 + 0][L];
        const bf16x8 al0 = *(const bf16x8*)&sm.s.Alo[b][whalf][wmg * 2 + 0][L];
        const bf16x8 ah1 = *(const bf16x8*)&sm.s.Ahi[b][whalf][wmg * 2 + 1][L];
        const bf16x8 al1 = *(const bf16x8*)&sm.s.Alo[b][whalf][wmg * 2 + 1][L];
#pragma unroll
        for (int n = 0; n < 2; ++n) {
            const int nt = wng * 2 + n;
            const bf16x8 whi = *(const bf16x8*)&sm.s.W[b][whalf][nt * 64 + L];
            const bf16x8 wlo = *(const bf16x8*)&sm.s.W[b][whalf][512 + nt * 64 + L];
            acc[0][n] = __builtin_amdgcn_mfma_f32_16x16x32_bf16(ah0, whi, acc[0][n], 0, 0, 0);
            acc[0][n] = __builtin_amdgcn_mfma_f32_16x16x32_bf16(ah0, wlo, acc[0][n], 0, 0, 0);
            acc[0][n] = __builtin_amdgcn_mfma_f32_16x16x32_bf16(al0, whi, acc[0][n], 0, 0, 0);
            acc[1][n] = __builtin_amdgcn_mfma_f32_16x16x32_bf16(ah1, whi, acc[1][n], 0, 0, 0);
            acc[1][n] = __builtin_amdgcn_mfma_f32_16x16x32_bf16(ah1, wlo, acc[1][n], 0, 0, 0);
            acc[1][n] = __builtin_amdgcn_mfma_f32_16x16x32_bf16(al1, whi, acc[1][n], 0, 0, 0);
        }
        __syncthreads();   // vmcnt(0)+lgkmcnt(0) drain lands AFTER compute
        b ^= 1;
    }
#undef STAGE

    // epilogue: C/D layout col(expert)=lane&15, row(token)=(lane>>4)*4+reg
    if (whalf == 0) {
#pragma unroll
        for (int m = 0; m < 2; ++m)
#pragma unroll
            for (int n = 0; n < 2; ++n) {
                const int e = (wng * 2 + n) * 16 + (L & 15);
                const float bv = bias[e];
#pragma unroll
                for (int r = 0; r < 4; ++r)
                    sm.L[(wmg * 2 + m) * 16 + (L >> 4) * 4 + r][e] = acc[m][n][r] + bv;
            }
    }
    __syncthreads();
    if (whalf == 1) {
#pragma unroll
        for (int m = 0; m < 2; ++m)
#pragma unroll
            for (int n = 0; n < 2; ++n) {
                const int e = (wng * 2 + n) * 16 + (L & 15);
#pragma unroll
                for (int r = 0; r < 4; ++r)
                    sm.L[(wmg * 2 + m) * 16 + (L >> 4) * 4 + r][e] += acc[m][n][r];
            }
    }
    __syncthreads();

    // top-5 scan (stable strict '>') + gap test + softmax + candidate record
    if (tid < MTM) {
        float v0 = -1e30f, v1 = -1e30f, v2 = -1e30f, v3 = -1e30f, v4 = -1e30f;
        int   i0 = 0, i1 = 0, i2 = 0, i3 = 0, i4 = 0;
        for (int e = 0; e < E_EXP; ++e) {
            const float x = sm.L[tid][e];
            if (x > v4) {
                if (x > v0)      { v4=v3;i4=i3; v3=v2;i3=i2; v2=v1;i2=i1; v1=v0;i1=i0; v0=x;i0=e; }
                else if (x > v1) { v4=v3;i4=i3; v3=v2;i3=i2; v2=v1;i2=i1; v1=x;i1=e; }
                else if (x > v2) { v4=v3;i4=i3; v3=v2;i3=i2; v2=x;i2=e; }
                else if (x > v3) { v4=v3;i4=i3; v3=x;i3=e; }
                else             { v4=x;i4=e; }
            }
        }
        const float g0 = v0 - v1, g1 = v1 - v2, g2 = v2 - v3, g3 = v3 - v4;
        float mg = g0 < g1 ? g0 : g1;
        mg = mg < g2 ? mg : g2;
        mg = mg < g3 ? mg : g3;

        const float e0x = expf(v0 - v0);
        const float e1x = expf(v1 - v0);
        const float e2x = expf(v2 - v0);
        const float e3x = expf(v3 - v0);
        const float s   = e0x + e1x + e2x + e3x;

        const int gt = t_base + tid;
        float* out_scores = out;
        float* out_idx    = out + (size_t)T_TOKENS * TOPK;
        out_scores[gt * 4 + 0] = e0x / s;
        out_scores[gt * 4 + 1] = e1x / s;
        out_scores[gt * 4 + 2] = e2x / s;
        out_scores[gt * 4 + 3] = e3x / s;
        out_idx[gt * 4 + 0] = (float)i0;
        out_idx[gt * 4 + 1] = (float)i1;
        out_idx[gt * 4 + 2] = (float)i2;
        out_idx[gt * 4 + 3] = (float)i3;

        if (mg < EPS_GAP) {
            const int p = atomicAdd(flag_count, 1);
            if (p < T_TOKENS) {
                flag_list[p] = gt;
                // collect candidates (ascending e): all logits >= v3 - EPS_GAP
                unsigned ids[8];
                int nc = 0;
                const float thr = v3 - EPS_GAP;
                for (int e = 0; e < E_EXP; ++e) {
                    if (sm.L[tid][e] >= thr) {
                        if (nc < 8) ids[nc] = (unsigned)e;
                        ++nc;
                    }
                }
                uint2 cd;
                if (nc > 8) {
                    cd.x = 0xFEu; cd.y = 0xFFFFFFFFu;   // full-scan sentinel
                } else {
                    for (int q = nc; q < 8; ++q) ids[q] = 0xFFu;
                    cd.x = ids[0] | (ids[1] << 8) | (ids[2] << 16) | (ids[3] << 24);
                    cd.y = ids[4] | (ids[5] << 8) | (ids[6] << 16) | (ids[7] << 24);
                }
                cand_list[p] = cd;
            }
        }
    }
}

// ---------------------------------------------------------------------------
// Candidate-limited recheck: exact f64 recompute of ONLY the candidate
// experts of each flagged token (A row staged to LDS; 8 slots x 32 lanes).
// Falls back to full 128-expert scan on the 0xFE sentinel (nc > 8).
// ---------------------------------------------------------------------------
__global__ __launch_bounds__(256) void router_recheck(
    const float* __restrict__ A, const float* __restrict__ W,
    const float* __restrict__ bias, float* __restrict__ out,
    const int* __restrict__ flag_count, const int* __restrict__ flag_list,
    const uint2* __restrict__ cand_list)
{
    __shared__ float  sA[H_DIM];        // 11.52 KB
    __shared__ double sLog[8];
    __shared__ int    sIds[8];
    __shared__ double sPart[256];
    __shared__ double sFull[E_EXP];

    int count = *flag_count;
    if (count > T_TOKENS) count = T_TOKENS;

    const int tid = threadIdx.x;

    for (int i = blockIdx.x; i < count; i += gridDim.x) {
        const int t = flag_list[i];
        const uint2 cd = cand_list[i];
        __syncthreads();   // previous iteration fully done before sA restage

        // stage A row (720 float4)
        for (int q = tid; q < H_DIM / 4; q += 256)
            *(float4*)&sA[q * 4] = *(const float4*)(A + (size_t)t * H_DIM + q * 4);
        __syncthreads();

        const bool full = ((cd.x & 0xFFu) == 0xFEu);
        if (!full) {
            const int sl = tid >> 5;     // candidate slot 0..7
            const int j  = tid & 31;     // lane within slot
            const unsigned e = (sl < 4 ? (cd.x >> (sl * 8)) : (cd.y >> ((sl - 4) * 8))) & 0xFFu;
            double sum = 0.0;
            if (e < E_EXP) {
                const float* wrow = W + (size_t)e * H_DIM;
                for (int k = j; k < H_DIM; k += 32)
                    sum += (double)sA[k] * (double)wrow[k];
            }
#pragma unroll
            for (int off = 16; off > 0; off >>= 1)
                sum += __shfl_down(sum, off, 32);
            if (j == 0) {
                sIds[sl] = (e < E_EXP) ? (int)e : -1;
                sLog[sl] = (e < E_EXP) ? (sum + (double)bias[e]) : -1e300;
            }
            __syncthreads();
            if (tid == 0) {
                double v0 = -1e300, v1 = -1e300, v2 = -1e300, v3 = -1e300;
                int    i0 = 0, i1 = 0, i2 = 0, i3 = 0;
                for (int q = 0; q < 8; ++q) {        // ascending expert id
                    if (sIds[q] < 0) continue;
                    const double x = sLog[q];
                    const int    id = sIds[q];
                    if (x > v3) {
                        if (x > v0)      { v3=v2;i3=i2; v2=v1;i2=i1; v1=v0;i1=i0; v0=x;i0=id; }
                        else if (x > v1) { v3=v2;i3=i2; v2=v1;i2=i1; v1=x;i1=id; }
                        else if (x > v2) { v3=v2;i3=i2; v2=x;i2=id; }
                        else             { v3=x;i3=id; }
                    }
                }
                const double e0x = exp(v0 - v0);
                const double e1x = exp(v1 - v0);
                const double e2x = exp(v2 - v0);
                const double e3x = exp(v3 - v0);
                const double s   = e0x + e1x + e2x + e3x;
                float* out_scores = out;
                float* out_idx    = out + (size_t)T_TOKENS * TOPK;
                out_scores[t * 4 + 0] = (float)(e0x / s);
                out_scores[t * 4 + 1] = (float)(e1x / s);
                out_scores[t * 4 + 2] = (float)(e2x / s);
                out_scores[t * 4 + 3] = (float)(e3x / s);
                out_idx[t * 4 + 0] = (float)i0;
                out_idx[t * 4 + 1] = (float)i1;
                out_idx[t * 4 + 2] = (float)i2;
                out_idx[t * 4 + 3] = (float)i3;
            }
        } else {
            // full 128-expert exact recompute (rare)
            const int e = tid & (E_EXP - 1);
            const int h = tid >> 7;
            const float* wrow = W + (size_t)e * H_DIM + h * KHALF;
            const float* arow = &sA[h * KHALF];
            double s0 = 0.0, s1 = 0.0;
            for (int k = 0; k < KHALF; k += 2) {
                s0 += (double)arow[k]     * (double)wrow[k];
                s1 += (double)arow[k + 1] * (double)wrow[k + 1];
            }
            sPart[tid] = s0 + s1;
            __syncthreads();
            if (h == 0) sFull[e] = sPart[e] + sPart[e + 128] + (double)bias[e];
            __syncthreads();
            if (tid == 0) {
                double v0 = -1e300, v1 = -1e300, v2 = -1e300, v3 = -1e300;
                int    i0 = 0, i1 = 0, i2 = 0, i3 = 0;
                for (int q = 0; q < E_EXP; ++q) {
                    const double x = sFull[q];
                    if (x > v3) {
                        if (x > v0)      { v3=v2;i3=i2; v2=v1;i2=i1; v1=v0;i1=i0; v0=x;i0=q; }
                        else if (x > v1) { v3=v2;i3=i2; v2=v1;i2=i1; v1=x;i1=q; }
                        else if (x > v2) { v3=v2;i3=i2; v2=x;i2=q; }
                        else             { v3=x;i3=q; }
                    }
                }
                const double e0x = exp(v0 - v0);
                const double e1x = exp(v1 - v0);
                const double e2x = exp(v2 - v0);
                const double e3x = exp(v3 - v0);
                const double s   = e0x + e1x + e2x + e3x;
                float* out_scores = out;
                float* out_idx    = out + (size_t)T_TOKENS * TOPK;
                out_scores[t * 4 + 0] = (float)(e0x / s);
                out_scores[t * 4 + 1] = (float)(e1x / s);
                out_scores[t * 4 + 2] = (float)(e2x / s);
                out_scores[t * 4 + 3] = (float)(e3x / s);
                out_idx[t * 4 + 0] = (float)i0;
                out_idx[t * 4 + 1] = (float)i1;
                out_idx[t * 4 + 2] = (float)i2;
                out_idx[t * 4 + 3] = (float)i3;
            }
        }
        __syncthreads();
    }
}

// ---------------------------------------------------------------------------
// Fallback main (ws too small for prep path): round-0 kernel, unchanged.
// ---------------------------------------------------------------------------
__global__ __launch_bounds__(512, 4) void router_main_fb(
    const float* __restrict__ A, const float* __restrict__ W,
    const float* __restrict__ bias, float* __restrict__ out,
    int* __restrict__ flag_count, int* __restrict__ flag_list)
{
    __shared__ __align__(16) uint2 sAhi[2][2][128];
    __shared__ __align__(16) uint2 sAlo[2][2][128];
    __shared__ __align__(16) uint4 sWhi[2][8][64];
    __shared__ __align__(16) uint4 sWlo[2][8][64];
    __shared__ float sL[MT][129];

    const int tid    = threadIdx.x;
    const int t_base = blockIdx.x * MT;
    const int wave  = tid >> 6;
    const int L     = tid & 63;
    const int whalf = wave >> 2;
    const int wm    = wave & 1;
    const int wn    = (wave >> 1) & 1;
    const int shalf = tid >> 8;
    const int tid_h = tid & 255;
    const int at = tid_h >> 3;
    const int ac = tid_h & 7;
    const int a_idx = (at >> 4) * 128 + ((((ac >> 1) << 4) | (at & 15)) << 1) + (ac & 1);
    const float* Ag = A + (size_t)(t_base + at) * H_DIM + shalf * KHALF + ac * 4;
    const int we  = tid_h >> 1;
    const int wq0 = (tid_h & 1) * 2;
    const float* Wg = W + (size_t)we * H_DIM + shalf * KHALF + wq0 * 8;
    const int w_nt = we >> 4;
    const int w_n  = we & 15;

    uint2* sAhiF = &sAhi[shalf][0][0];
    uint2* sAloF = &sAlo[shalf][0][0];

    f32x4 acc[4];
#pragma unroll
    for (int i = 0; i < 4; ++i) { f32x4 z = {0.f, 0.f, 0.f, 0.f}; acc[i] = z; }

    for (int k0 = 0; k0 < KHALF; k0 += KC) {
        const float4 av  = *(const float4*)(Ag + k0);
        const float4 wv0 = *(const float4*)(Wg + k0);
        const float4 wv1 = *(const float4*)(Wg + k0 + 4);
        const float4 wv2 = *(const float4*)(Wg + k0 + 8);
        const float4 wv3 = *(const float4*)(Wg + k0 + 12);

        uint2 ahp, alp;
        split2(av.x, av.y, ahp.x, alp.x);
        split2(av.z, av.w, ahp.y, alp.y);
        uint4 whp0, wlp0, whp1, wlp1;
        split2(wv0.x, wv0.y, whp0.x, wlp0.x);
        split2(wv0.z, wv0.w, whp0.y, wlp0.y);
        split2(wv1.x, wv1.y, whp0.z, wlp0.z);
        split2(wv1.z, wv1.w, whp0.w, wlp0.w);
        split2(wv2.x, wv2.y, whp1.x, wlp1.x);
        split2(wv2.z, wv2.w, whp1.y, wlp1.y);
        split2(wv3.x, wv3.y, whp1.z, wlp1.z);
        split2(wv3.z, wv3.w, whp1.w, wlp1.w);

        __syncthreads();
        sAhiF[a_idx] = ahp;
        sAloF[a_idx] = alp;
        sWhi[shalf][w_nt][((wq0 + 0) << 4) | w_n] = whp0;
        sWhi[shalf][w_nt][((wq0 + 1) << 4) | w_n] = whp1;
        sWlo[shalf][w_nt][((wq0 + 0) << 4) | w_n] = wlp0;
        sWlo[shalf][w_nt][((wq0 + 1) << 4) | w_n] = wlp1;
        __syncthreads();

        const bf16x8 ahi = *(const bf16x8*)&sAhi[whalf][wm][L * 2];
        const bf16x8 alo = *(const bf16x8*)&sAlo[whalf][wm][L * 2];
#pragma unroll
        for (int i = 0; i < 4; ++i) {
            const int nt = wn * 4 + i;
            const bf16x8 whi = *(const bf16x8*)&sWhi[whalf][nt][L];
            const bf16x8 wlo = *(const bf16x8*)&sWlo[whalf][nt][L];
            acc[i] = __builtin_amdgcn_mfma_f32_16x16x32_bf16(ahi, whi, acc[i], 0, 0, 0);
            acc[i] = __builtin_amdgcn_mfma_f32_16x16x32_bf16(ahi, wlo, acc[i], 0, 0, 0);
            acc[i] = __builtin_amdgcn_mfma_f32_16x16x32_bf16(alo, whi, acc[i], 0, 0, 0);
        }
    }

    __syncthreads();
    if (whalf == 0) {
#pragma unroll
        for (int i = 0; i < 4; ++i) {
            const int e = wn * 64 + i * 16 + (L & 15);
            const float b = bias[e];
#pragma unroll
            for (int r = 0; r < 4; ++r)
                sL[wm * 16 + (L >> 4) * 4 + r][e] = acc[i][r] + b;
        }
    }
    __syncthreads();
    if (whalf == 1) {
#pragma unroll
        for (int i = 0; i < 4; ++i) {
            const int e = wn * 64 + i * 16 + (L & 15);
#pragma unroll
            for (int r = 0; r < 4; ++r)
                sL[wm * 16 + (L >> 4) * 4 + r][e] += acc[i][r];
        }
    }
    __syncthreads();

    if (tid < MT) {
        float v0 = -1e30f, v1 = -1e30f, v2 = -1e30f, v3 = -1e30f, v4 = -1e30f;
        int   i0 = 0, i1 = 0, i2 = 0, i3 = 0, i4 = 0;
        for (int e = 0; e < E_EXP; ++e) {
            const float x = sL[tid][e];
            if (x > v4) {
                if (x > v0)      { v4=v3;i4=i3; v3=v2;i3=i2; v2=v1;i2=i1; v1=v0;i1=i0; v0=x;i0=e; }
                else if (x > v1) { v4=v3;i4=i3; v3=v2;i3=i2; v2=v1;i2=i1; v1=x;i1=e; }
                else if (x > v2) { v4=v3;i4=i3; v3=v2;i3=i2; v2=x;i2=e; }
                else if (x > v3) { v4=v3;i4=i3; v3=x;i3=e; }
                else             { v4=x;i4=e; }
            }
        }
        const float g0 = v0 - v1, g1 = v1 - v2, g2 = v2 - v3, g3 = v3 - v4;
        float mg = g0 < g1 ? g0 : g1;
        mg = mg < g2 ? mg : g2;
        mg = mg < g3 ? mg : g3;

        const float e0x = expf(v0 - v0);
        const float e1x = expf(v1 - v0);
        const float e2x = expf(v2 - v0);
        const float e3x = expf(v3 - v0);
        const float s   = e0x + e1x + e2x + e3x;

        const int gt = t_base + tid;
        float* out_scores = out;
        float* out_idx    = out + (size_t)T_TOKENS * TOPK;
        out_scores[gt * 4 + 0] = e0x / s;
        out_scores[gt * 4 + 1] = e1x / s;
        out_scores[gt * 4 + 2] = e2x / s;
        out_scores[gt * 4 + 3] = e3x / s;
        out_idx[gt * 4 + 0] = (float)i0;
        out_idx[gt * 4 + 1] = (float)i1;
        out_idx[gt * 4 + 2] = (float)i2;
        out_idx[gt * 4 + 3] = (float)i3;

        if (mg < EPS_GAP) {
            const int p = atomicAdd(flag_count, 1);
            if (p < T_TOKENS) flag_list[p] = gt;
        }
    }
}

// ---------------------------------------------------------------------------
// Fallback recheck (full 128-expert, reads A from global) — unchanged.
// ---------------------------------------------------------------------------
__global__ __launch_bounds__(256) void router_recheck_fb(
    const float* __restrict__ A, const float* __restrict__ W,
    const float* __restrict__ bias, float* __restrict__ out,
    const int* __restrict__ flag_count, const int* __restrict__ flag_list)
{
    __shared__ double sPart[256];
    __shared__ double sLog[E_EXP];

    int count = *flag_count;
    if (count > T_TOKENS) count = T_TOKENS;

    const int tid = threadIdx.x;
    const int e   = tid & (E_EXP - 1);
    const int h   = tid >> 7;

    for (int i = blockIdx.x; i < count; i += gridDim.x) {
        const int t = flag_list[i];
        const float* arow = A + (size_t)t * H_DIM + h * KHALF;
        const float* wrow = W + (size_t)e * H_DIM + h * KHALF;

        double s0 = 0.0, s1 = 0.0, s2 = 0.0, s3 = 0.0;
        float4 a[8], w[8];
#pragma unroll
        for (int q = 0; q < 8; ++q) {
            a[q] = *(const float4*)(arow + q * 4);
            w[q] = *(const float4*)(wrow + q * 4);
        }
        for (int it = 0; it < KHALF / 32 - 1; ++it) {
            const float* ap = arow + (it + 1) * 32;
            const float* wp = wrow + (it + 1) * 32;
            float4 na[8], nw[8];
#pragma unroll
            for (int q = 0; q < 8; ++q) {
                na[q] = *(const float4*)(ap + q * 4);
                nw[q] = *(const float4*)(wp + q * 4);
            }
#pragma unroll
            for (int q = 0; q < 8; ++q) {
                s0 += (double)a[q].x * (double)w[q].x;
                s1 += (double)a[q].y * (double)w[q].y;
                s2 += (double)a[q].z * (double)w[q].z;
                s3 += (double)a[q].w * (double)w[q].w;
            }
#pragma unroll
            for (int q = 0; q < 8; ++q) { a[q] = na[q]; w[q] = nw[q]; }
        }
#pragma unroll
        for (int q = 0; q < 8; ++q) {
            s0 += (double)a[q].x * (double)w[q].x;
            s1 += (double)a[q].y * (double)w[q].y;
            s2 += (double)a[q].z * (double)w[q].z;
            s3 += (double)a[q].w * (double)w[q].w;
        }
        sPart[tid] = (s0 + s1) + (s2 + s3);
        __syncthreads();
        if (h == 0) sLog[e] = sPart[e] + sPart[e + 128] + (double)bias[e];
        __syncthreads();

        if (tid == 0) {
            double v0 = -1e300, v1 = -1e300, v2 = -1e300, v3 = -1e300;
            int    i0 = 0, i1 = 0, i2 = 0, i3 = 0;
            for (int q = 0; q < E_EXP; ++q) {
                const double x = sLog[q];
                if (x > v3) {
                    if (x > v0)      { v3=v2;i3=i2; v2=v1;i2=i1; v1=v0;i1=i0; v0=x;i0=q; }
                    else if (x > v1) { v3=v2;i3=i2; v2=v1;i2=i1; v1=x;i1=q; }
                    else if (x > v2) { v3=v2;i3=i2; v2=x;i2=q; }
                    else             { v3=x;i3=q; }
                }
            }
            const double e0x = exp(v0 - v0);
            const double e1x = exp(v1 - v0);
            const double e2x = exp(v2 - v0);
            const double e3x = exp(v3 - v0);
            const double s   = e0x + e1x + e2x + e3x;
            float* out_scores = out;
            float* out_idx    = out + (size_t)T_TOKENS * TOPK;
            out_scores[t * 4 + 0] = (float)(e0x / s);
            out_scores[t * 4 + 1] = (float)(e1x / s);
            out_scores[t * 4 + 2] = (float)(e2x / s);
            out_scores[t * 4 + 3] = (float)(e3x / s);
            out_idx[t * 4 + 0] = (float)i0;
            out_idx[t * 4 + 1] = (float)i1;
            out_idx[t * 4 + 2] = (float)i2;
            out_idx[t * 4 + 3] = (float)i3;
        }
        __syncthreads();
    }
}

extern "C" void kernel_launch(void* const* d_in, const int* in_sizes, int n_in,
                              void* d_out, int out_size, void* d_ws, size_t ws_size,
                              hipStream_t stream) {
    const float* A    = (const float*)d_in[0];
    const float* W    = (const float*)d_in[1];
    const float* bias = (const float*)d_in[2];
    float* out = (float*)d_out;

    if (ws_size >= (size_t)WS_NEED) {
        int*   flag_count = (int*)d_ws;
        uint4* wsW        = (uint4*)((char*)d_ws + WS_WOFF);
        int*   flag_list  = (int*)((char*)d_ws + WS_FLOFF);
        uint2* cand_list  = (uint2*)((char*)d_ws + WS_CAOFF);
        hipMemsetAsync(flag_count, 0, sizeof(int), stream);
        prep_w<<<dim3((NCHUNK * 512) / 256), dim3(256), 0, stream>>>(W, wsW);
        router_main<<<dim3(T_TOKENS / MTM), dim3(1024), 0, stream>>>(
            A, wsW, bias, out, flag_count, flag_list, cand_list);
        router_recheck<<<dim3(512), dim3(256), 0, stream>>>(
            A, W, bias, out, flag_count, flag_list, cand_list);
    } else {
        int* flag_count = (int*)d_ws;
        int* flag_list  = (int*)d_ws + 1;
        hipMemsetAsync(flag_count, 0, sizeof(int), stream);
        router_main_fb<<<dim3(T_TOKENS / MT), dim3(512), 0, stream>>>(A, W, bias, out,
                                                                      flag_count, flag_list);
        router_recheck_fb<<<dim3(512), dim3(256), 0, stream>>>(A, W, bias, out,
                                                               flag_count, flag_list);
    }
}

// Round 5
// 344.187 us; speedup vs baseline: 1.4037x; 1.0310x over previous
//
#include <hip/hip_runtime.h>
#include <hip/hip_bf16.h>
#include <math.h>

#define T_TOKENS 16384
#define H_DIM    2880
#define KHALF    1440      // H_DIM/2, per in-block K-split half
#define E_EXP    128
#define TOPK     4
#define MT       32        // fb kernel tokens per block
#define MTM      64        // main kernel tokens per block
#define KC       32        // K chunk per iteration
#define NCHUNK   (H_DIM / KC)          // 90
#define NCHUNK_H (KHALF / KC)          // 45
#define EPS_GAP  5e-4f

// d_ws layout (prep path):
//   [0..63]                   : flag_count (int at offset 0) + pad
//   [64 .. 64+1.44MB)         : W frags, [chunk kc][hi:512 | lo:512 uint4]
//   [WS_FLOFF .. +64KB)       : flag_list (T_TOKENS ints)
//   [WS_CAOFF .. +128KB)      : cand_list (T_TOKENS uint2: 8 expert bytes)
#define WS_WOFF   64
#define WS_WBYTES (NCHUNK * 1024 * 16)
#define WS_FLOFF  (WS_WOFF + WS_WBYTES)
#define WS_CAOFF  (WS_FLOFF + T_TOKENS * 4)
#define WS_NEED   (WS_CAOFF + T_TOKENS * 8)

typedef __bf16 bf16x8 __attribute__((ext_vector_type(8)));
typedef float  f32x4  __attribute__((ext_vector_type(4)));

// packed RNE split: (a,b) -> hi word [b_hi|a_hi], lo word [b_lo|a_lo]
__device__ __forceinline__ void split2(float a, float b,
                                       unsigned int& hi, unsigned int& lo) {
    float2 p; p.x = a; p.y = b;
    __hip_bfloat162 h = __float22bfloat162_rn(p);
    unsigned int hu; __builtin_memcpy(&hu, &h, 4);
    float2 r;
    r.x = a - __uint_as_float((hu & 0xffffu) << 16);
    r.y = b - __uint_as_float(hu & 0xffff0000u);
    __hip_bfloat162 l = __float22bfloat162_rn(r);
    unsigned int lu; __builtin_memcpy(&lu, &l, 4);
    hi = hu; lo = lu;
}

// ---------------------------------------------------------------------------
// Prep: split W into MFMA-fragment-ordered bf16 hi/lo (unchanged layout).
// Frag (kc, nt, L): e = nt*16 + (L&15), k = kc*32 + (L>>4)*8 .. +7.
// ---------------------------------------------------------------------------
__global__ __launch_bounds__(256) void prep_w(const float* __restrict__ W,
                                              uint4* __restrict__ wsW) {
    const int f   = blockIdx.x * 256 + threadIdx.x;   // 0 .. 46079
    const int kc  = f >> 9;
    const int rem = f & 511;
    const int nt  = rem >> 6;
    const int L   = rem & 63;
    const int e   = nt * 16 + (L & 15);
    const int k   = kc * KC + (L >> 4) * 8;
    const float* p = W + (size_t)e * H_DIM + k;
    const float4 x0 = *(const float4*)p;
    const float4 x1 = *(const float4*)(p + 4);
    uint4 hi, lo;
    split2(x0.x, x0.y, hi.x, lo.x);
    split2(x0.z, x0.w, hi.y, lo.y);
    split2(x1.x, x1.y, hi.z, lo.z);
    split2(x1.z, x1.w, hi.w, lo.w);
    wsW[(size_t)kc * 1024 + nt * 64 + L]       = hi;
    wsW[(size_t)kc * 1024 + 512 + nt * 64 + L] = lo;
}

// ---------------------------------------------------------------------------
// Main: MT=64, 1024 threads (16 waves), grid 256 (1 block/CU).
// 16x16x32 bf16x3, in-block split-K over 2 halves.
// Pipeline: counted-vmcnt single-barrier double buffer (T3/T4): per iter
//   [gl_lds W(it+1)->b^1 x2] sched_barrier [A reg prefetch it+2 x1]
//   [split2(av it+1) + 2x ds_write_b64 -> b^1] [compute b]
//   s_waitcnt vmcnt(1) lgkmcnt(0); s_barrier
// vmcnt(1) retires only the W gl_lds pair; the A prefetch stays in flight
// across the barrier (retired by the compiler's counted wait at next split2).
// A staging spread over ALL 16 waves (uniform vmem count): token-major map,
// 256B-contiguous global reads, bank-balanced ds_write_b64.
// ---------------------------------------------------------------------------
__global__ __launch_bounds__(1024, 4) void router_main(
    const float* __restrict__ A, const uint4* __restrict__ wsW,
    const float* __restrict__ bias, float* __restrict__ out,
    int* __restrict__ flag_count, int* __restrict__ flag_list,
    uint2* __restrict__ cand_list)
{
    union SMem {
        struct {
            uint4 W  [2][2][1024];    // [buf][half][hi:512|lo:512 frags] 64 KB
            uint4 Ahi[2][2][4][64];   // [buf][half][mt][lane]            16 KB
            uint4 Alo[2][2][4][64];   //                                  16 KB
        } s;
        float L[MTM][129];            // logits (epilogue only)           33 KB
    };
    __shared__ SMem sm;

    const int tid    = threadIdx.x;
    const int t_base = blockIdx.x * MTM;

    const int wave  = tid >> 6;
    const int L     = tid & 63;
    const int whalf = wave >> 3;        // K half this wave computes
    const int wmg   = (wave >> 2) & 1;  // m-group: m-tiles wmg*2, wmg*2+1
    const int wng   = wave & 3;         // n-group: n-tiles wng*2, wng*2+1

    // W staging: wave stages 2 frag-chunks of its half's K-chunk
    const int shalf = whalf;
    const int wv    = wave & 7;
    const uint4* wsrc = wsW + (size_t)(shalf * NCHUNK_H) * 1024 + (wv * 2) * 64 + L;

    // A staging (all 1024 threads, token-major): thread -> (token, k-quad).
    // Global: 16 consecutive threads read one token's 2x128B row segments.
    // LDS: uint2 writes at slot [ah][amt][oct*16+t16], dword-pair 'sub'.
    const int at   = tid >> 4;          // token 0..63
    const int kq   = tid & 15;          // k-quad 0..15 (covers both halves)
    const int ah   = kq >> 3;
    const int oct  = (kq >> 1) & 3;
    const int sub  = kq & 1;
    const int amt  = at >> 4;
    const int t16  = at & 15;
    const float* Ag = A + (size_t)(t_base + at) * H_DIM + ah * KHALF + oct * 8 + sub * 4;

    f32x4 acc[2][2];
#pragma unroll
    for (int m = 0; m < 2; ++m)
#pragma unroll
        for (int n = 0; n < 2; ++n) { f32x4 z = {0.f, 0.f, 0.f, 0.f}; acc[m][n] = z; }

#define GLDS(SRC, DST) \
    __builtin_amdgcn_global_load_lds( \
        (const __attribute__((address_space(1))) void*)(SRC), \
        (__attribute__((address_space(3))) void*)(DST), 16, 0, 0)

#define STAGE_W(NB, IT)                                                        \
    {                                                                          \
        const uint4* wc = wsrc + (size_t)(IT) * 1024;                          \
        GLDS(wc,      &sm.s.W[NB][shalf][(wv * 2 + 0) * 64]);                  \
        GLDS(wc + 64, &sm.s.W[NB][shalf][(wv * 2 + 1) * 64]);                  \
    }

#define STAGE_A(NB)                                                            \
    {                                                                          \
        uint2 h2, l2;                                                          \
        split2(av.x, av.y, h2.x, l2.x);                                        \
        split2(av.z, av.w, h2.y, l2.y);                                        \
        ((uint2*)&sm.s.Ahi[NB][ah][amt][oct * 16 + t16])[sub] = h2;            \
        ((uint2*)&sm.s.Alo[NB][ah][amt][oct * 16 + t16])[sub] = l2;            \
    }

#define COMPUTE(NB)                                                            \
    {                                                                          \
        const bf16x8 ah0 = *(const bf16x8*)&sm.s.Ahi[NB][whalf][wmg * 2 + 0][L]; \
        const bf16x8 al0 = *(const bf16x8*)&sm.s.Alo[NB][whalf][wmg * 2 + 0][L]; \
        const bf16x8 ah1 = *(const bf16x8*)&sm.s.Ahi[NB][whalf][wmg * 2 + 1][L]; \
        const bf16x8 al1 = *(const bf16x8*)&sm.s.Alo[NB][whalf][wmg * 2 + 1][L]; \
        _Pragma("unroll")                                                      \
        for (int n = 0; n < 2; ++n) {                                          \
            const int nt = wng * 2 + n;                                        \
            const bf16x8 whi = *(const bf16x8*)&sm.s.W[NB][whalf][nt * 64 + L]; \
            const bf16x8 wlo = *(const bf16x8*)&sm.s.W[NB][whalf][512 + nt * 64 + L]; \
            acc[0][n] = __builtin_amdgcn_mfma_f32_16x16x32_bf16(ah0, whi, acc[0][n], 0, 0, 0); \
            acc[0][n] = __builtin_amdgcn_mfma_f32_16x16x32_bf16(ah0, wlo, acc[0][n], 0, 0, 0); \
            acc[0][n] = __builtin_amdgcn_mfma_f32_16x16x32_bf16(al0, whi, acc[0][n], 0, 0, 0); \
            acc[1][n] = __builtin_amdgcn_mfma_f32_16x16x32_bf16(ah1, whi, acc[1][n], 0, 0, 0); \
            acc[1][n] = __builtin_amdgcn_mfma_f32_16x16x32_bf16(ah1, wlo, acc[1][n], 0, 0, 0); \
            acc[1][n] = __builtin_amdgcn_mfma_f32_16x16x32_bf16(al1, whi, acc[1][n], 0, 0, 0); \
        }                                                                      \
    }

#define CBAR(VM)                                                               \
    asm volatile("s_waitcnt vmcnt(" #VM ") lgkmcnt(0)" ::: "memory");          \
    __builtin_amdgcn_s_barrier();                                              \
    __builtin_amdgcn_sched_barrier(0);

    // ---- prologue: chunk 0 into buf 0, prefetch A chunk 1 ----
    float4 av = *(const float4*)Ag;                 // A chunk 0
    STAGE_A(0);
    STAGE_W(0, 0);
    __builtin_amdgcn_sched_barrier(0);              // keep W older than next A load
    av = *(const float4*)(Ag + KC);                 // A chunk 1 (in flight over barrier)
    CBAR(1)                                         // retire W(0) pair only

    int b = 0;
    for (int it = 0; it < NCHUNK_H - 2; ++it) {     // it = 0..42
        STAGE_W(b ^ 1, it + 1);
        __builtin_amdgcn_sched_barrier(0);
        const float4 avn = *(const float4*)(Ag + (it + 2) * KC);
        STAGE_A(b ^ 1);                             // split2 waits av (counted)
        av = avn;
        COMPUTE(b);
        CBAR(1)                                     // retire this iter's W pair
        b ^= 1;
    }
    // it = 43: stage chunk 44, no A prefetch -> drain fully at barrier
    {
        STAGE_W(b ^ 1, NCHUNK_H - 1);
        STAGE_A(b ^ 1);
        COMPUTE(b);
        CBAR(0)
        b ^= 1;
    }
    // it = 44: compute only
    COMPUTE(b);
    __syncthreads();                                // full drain before L overlay

#undef GLDS
#undef STAGE_W
#undef STAGE_A
#undef COMPUTE
#undef CBAR

    // epilogue: C/D layout col(expert)=lane&15, row(token)=(lane>>4)*4+reg
    if (whalf == 0) {
#pragma unroll
        for (int m = 0; m < 2; ++m)
#pragma unroll
            for (int n = 0; n < 2; ++n) {
                const int e = (wng * 2 + n) * 16 + (L & 15);
                const float bv = bias[e];
#pragma unroll
                for (int r = 0; r < 4; ++r)
                    sm.L[(wmg * 2 + m) * 16 + (L >> 4) * 4 + r][e] = acc[m][n][r] + bv;
            }
    }
    __syncthreads();
    if (whalf == 1) {
#pragma unroll
        for (int m = 0; m < 2; ++m)
#pragma unroll
            for (int n = 0; n < 2; ++n) {
                const int e = (wng * 2 + n) * 16 + (L & 15);
#pragma unroll
                for (int r = 0; r < 4; ++r)
                    sm.L[(wmg * 2 + m) * 16 + (L >> 4) * 4 + r][e] += acc[m][n][r];
            }
    }
    __syncthreads();

    // top-5 scan (stable strict '>') + gap test + softmax + candidate record
    if (tid < MTM) {
        float v0 = -1e30f, v1 = -1e30f, v2 = -1e30f, v3 = -1e30f, v4 = -1e30f;
        int   i0 = 0, i1 = 0, i2 = 0, i3 = 0, i4 = 0;
        for (int e = 0; e < E_EXP; ++e) {
            const float x = sm.L[tid][e];
            if (x > v4) {
                if (x > v0)      { v4=v3;i4=i3; v3=v2;i3=i2; v2=v1;i2=i1; v1=v0;i1=i0; v0=x;i0=e; }
                else if (x > v1) { v4=v3;i4=i3; v3=v2;i3=i2; v2=v1;i2=i1; v1=x;i1=e; }
                else if (x > v2) { v4=v3;i4=i3; v3=v2;i3=i2; v2=x;i2=e; }
                else if (x > v3) { v4=v3;i4=i3; v3=x;i3=e; }
                else             { v4=x;i4=e; }
            }
        }
        const float g0 = v0 - v1, g1 = v1 - v2, g2 = v2 - v3, g3 = v3 - v4;
        float mg = g0 < g1 ? g0 : g1;
        mg = mg < g2 ? mg : g2;
        mg = mg < g3 ? mg : g3;

        const float e0x = expf(v0 - v0);
        const float e1x = expf(v1 - v0);
        const float e2x = expf(v2 - v0);
        const float e3x = expf(v3 - v0);
        const float s   = e0x + e1x + e2x + e3x;

        const int gt = t_base + tid;
        float* out_scores = out;
        float* out_idx    = out + (size_t)T_TOKENS * TOPK;
        out_scores[gt * 4 + 0] = e0x / s;
        out_scores[gt * 4 + 1] = e1x / s;
        out_scores[gt * 4 + 2] = e2x / s;
        out_scores[gt * 4 + 3] = e3x / s;
        out_idx[gt * 4 + 0] = (float)i0;
        out_idx[gt * 4 + 1] = (float)i1;
        out_idx[gt * 4 + 2] = (float)i2;
        out_idx[gt * 4 + 3] = (float)i3;

        if (mg < EPS_GAP) {
            const int p = atomicAdd(flag_count, 1);
            if (p < T_TOKENS) {
                flag_list[p] = gt;
                // collect candidates (ascending e): all logits >= v3 - EPS_GAP
                unsigned ids[8];
                int nc = 0;
                const float thr = v3 - EPS_GAP;
                for (int e = 0; e < E_EXP; ++e) {
                    if (sm.L[tid][e] >= thr) {
                        if (nc < 8) ids[nc] = (unsigned)e;
                        ++nc;
                    }
                }
                uint2 cd;
                if (nc > 8) {
                    cd.x = 0xFEu; cd.y = 0xFFFFFFFFu;   // full-scan sentinel
                } else {
                    for (int q = nc; q < 8; ++q) ids[q] = 0xFFu;
                    cd.x = ids[0] | (ids[1] << 8) | (ids[2] << 16) | (ids[3] << 24);
                    cd.y = ids[4] | (ids[5] << 8) | (ids[6] << 16) | (ids[7] << 24);
                }
                cand_list[p] = cd;
            }
        }
    }
}

// ---------------------------------------------------------------------------
// Candidate-limited recheck: exact f64 recompute of ONLY the candidate
// experts of each flagged token (A row staged to LDS; 8 slots x 32 lanes).
// Falls back to full 128-expert scan on the 0xFE sentinel (nc > 8).
// ---------------------------------------------------------------------------
__global__ __launch_bounds__(256) void router_recheck(
    const float* __restrict__ A, const float* __restrict__ W,
    const float* __restrict__ bias, float* __restrict__ out,
    const int* __restrict__ flag_count, const int* __restrict__ flag_list,
    const uint2* __restrict__ cand_list)
{
    __shared__ float  sA[H_DIM];        // 11.52 KB
    __shared__ double sLog[8];
    __shared__ int    sIds[8];
    __shared__ double sPart[256];
    __shared__ double sFull[E_EXP];

    int count = *flag_count;
    if (count > T_TOKENS) count = T_TOKENS;

    const int tid = threadIdx.x;

    for (int i = blockIdx.x; i < count; i += gridDim.x) {
        const int t = flag_list[i];
        const uint2 cd = cand_list[i];
        __syncthreads();   // previous iteration fully done before sA restage

        // stage A row (720 float4)
        for (int q = tid; q < H_DIM / 4; q += 256)
            *(float4*)&sA[q * 4] = *(const float4*)(A + (size_t)t * H_DIM + q * 4);
        __syncthreads();

        const bool full = ((cd.x & 0xFFu) == 0xFEu);
        if (!full) {
            const int sl = tid >> 5;     // candidate slot 0..7
            const int j  = tid & 31;     // lane within slot
            const unsigned e = (sl < 4 ? (cd.x >> (sl * 8)) : (cd.y >> ((sl - 4) * 8))) & 0xFFu;
            double sum = 0.0;
            if (e < E_EXP) {
                const float* wrow = W + (size_t)e * H_DIM;
                for (int k = j; k < H_DIM; k += 32)
                    sum += (double)sA[k] * (double)wrow[k];
            }
#pragma unroll
            for (int off = 16; off > 0; off >>= 1)
                sum += __shfl_down(sum, off, 32);
            if (j == 0) {
                sIds[sl] = (e < E_EXP) ? (int)e : -1;
                sLog[sl] = (e < E_EXP) ? (sum + (double)bias[e]) : -1e300;
            }
            __syncthreads();
            if (tid == 0) {
                double v0 = -1e300, v1 = -1e300, v2 = -1e300, v3 = -1e300;
                int    i0 = 0, i1 = 0, i2 = 0, i3 = 0;
                for (int q = 0; q < 8; ++q) {        // ascending expert id
                    if (sIds[q] < 0) continue;
                    const double x = sLog[q];
                    const int    id = sIds[q];
                    if (x > v3) {
                        if (x > v0)      { v3=v2;i3=i2; v2=v1;i2=i1; v1=v0;i1=i0; v0=x;i0=id; }
                        else if (x > v1) { v3=v2;i3=i2; v2=v1;i2=i1; v1=x;i1=id; }
                        else if (x > v2) { v3=v2;i3=i2; v2=x;i2=id; }
                        else             { v3=x;i3=id; }
                    }
                }
                const double e0x = exp(v0 - v0);
                const double e1x = exp(v1 - v0);
                const double e2x = exp(v2 - v0);
                const double e3x = exp(v3 - v0);
                const double s   = e0x + e1x + e2x + e3x;
                float* out_scores = out;
                float* out_idx    = out + (size_t)T_TOKENS * TOPK;
                out_scores[t * 4 + 0] = (float)(e0x / s);
                out_scores[t * 4 + 1] = (float)(e1x / s);
                out_scores[t * 4 + 2] = (float)(e2x / s);
                out_scores[t * 4 + 3] = (float)(e3x / s);
                out_idx[t * 4 + 0] = (float)i0;
                out_idx[t * 4 + 1] = (float)i1;
                out_idx[t * 4 + 2] = (float)i2;
                out_idx[t * 4 + 3] = (float)i3;
            }
        } else {
            // full 128-expert exact recompute (rare)
            const int e = tid & (E_EXP - 1);
            const int h = tid >> 7;
            const float* wrow = W + (size_t)e * H_DIM + h * KHALF;
            const float* arow = &sA[h * KHALF];
            double s0 = 0.0, s1 = 0.0;
            for (int k = 0; k < KHALF; k += 2) {
                s0 += (double)arow[k]     * (double)wrow[k];
                s1 += (double)arow[k + 1] * (double)wrow[k + 1];
            }
            sPart[tid] = s0 + s1;
            __syncthreads();
            if (h == 0) sFull[e] = sPart[e] + sPart[e + 128] + (double)bias[e];
            __syncthreads();
            if (tid == 0) {
                double v0 = -1e300, v1 = -1e300, v2 = -1e300, v3 = -1e300;
                int    i0 = 0, i1 = 0, i2 = 0, i3 = 0;
                for (int q = 0; q < E_EXP; ++q) {
                    const double x = sFull[q];
                    if (x > v3) {
                        if (x > v0)      { v3=v2;i3=i2; v2=v1;i2=i1; v1=v0;i1=i0; v0=x;i0=q; }
                        else if (x > v1) { v3=v2;i3=i2; v2=v1;i2=i1; v1=x;i1=q; }
                        else if (x > v2) { v3=v2;i3=i2; v2=x;i2=q; }
                        else             { v3=x;i3=q; }
                    }
                }
                const double e0x = exp(v0 - v0);
                const double e1x = exp(v1 - v0);
                const double e2x = exp(v2 - v0);
                const double e3x = exp(v3 - v0);
                const double s   = e0x + e1x + e2x + e3x;
                float* out_scores = out;
                float* out_idx    = out + (size_t)T_TOKENS * TOPK;
                out_scores[t * 4 + 0] = (float)(e0x / s);
                out_scores[t * 4 + 1] = (float)(e1x / s);
                out_scores[t * 4 + 2] = (float)(e2x / s);
                out_scores[t * 4 + 3] = (float)(e3x / s);
                out_idx[t * 4 + 0] = (float)i0;
                out_idx[t * 4 + 1] = (float)i1;
                out_idx[t * 4 + 2] = (float)i2;
                out_idx[t * 4 + 3] = (float)i3;
            }
        }
        __syncthreads();
    }
}

// ---------------------------------------------------------------------------
// Fallback main (ws too small for prep path): round-0 kernel, unchanged.
// ---------------------------------------------------------------------------
__global__ __launch_bounds__(512, 4) void router_main_fb(
    const float* __restrict__ A, const float* __restrict__ W,
    const float* __restrict__ bias, float* __restrict__ out,
    int* __restrict__ flag_count, int* __restrict__ flag_list)
{
    __shared__ __align__(16) uint2 sAhi[2][2][128];
    __shared__ __align__(16) uint2 sAlo[2][2][128];
    __shared__ __align__(16) uint4 sWhi[2][8][64];
    __shared__ __align__(16) uint4 sWlo[2][8][64];
    __shared__ float sL[MT][129];

    const int tid    = threadIdx.x;
    const int t_base = blockIdx.x * MT;
    const int wave  = tid >> 6;
    const int L     = tid & 63;
    const int whalf = wave >> 2;
    const int wm    = wave & 1;
    const int wn    = (wave >> 1) & 1;
    const int shalf = tid >> 8;
    const int tid_h = tid & 255;
    const int at = tid_h >> 3;
    const int ac = tid_h & 7;
    const int a_idx = (at >> 4) * 128 + ((((ac >> 1) << 4) | (at & 15)) << 1) + (ac & 1);
    const float* Ag = A + (size_t)(t_base + at) * H_DIM + shalf * KHALF + ac * 4;
    const int we  = tid_h >> 1;
    const int wq0 = (tid_h & 1) * 2;
    const float* Wg = W + (size_t)we * H_DIM + shalf * KHALF + wq0 * 8;
    const int w_nt = we >> 4;
    const int w_n  = we & 15;

    uint2* sAhiF = &sAhi[shalf][0][0];
    uint2* sAloF = &sAlo[shalf][0][0];

    f32x4 acc[4];
#pragma unroll
    for (int i = 0; i < 4; ++i) { f32x4 z = {0.f, 0.f, 0.f, 0.f}; acc[i] = z; }

    for (int k0 = 0; k0 < KHALF; k0 += KC) {
        const float4 av  = *(const float4*)(Ag + k0);
        const float4 wv0 = *(const float4*)(Wg + k0);
        const float4 wv1 = *(const float4*)(Wg + k0 + 4);
        const float4 wv2 = *(const float4*)(Wg + k0 + 8);
        const float4 wv3 = *(const float4*)(Wg + k0 + 12);

        uint2 ahp, alp;
        split2(av.x, av.y, ahp.x, alp.x);
        split2(av.z, av.w, ahp.y, alp.y);
        uint4 whp0, wlp0, whp1, wlp1;
        split2(wv0.x, wv0.y, whp0.x, wlp0.x);
        split2(wv0.z, wv0.w, whp0.y, wlp0.y);
        split2(wv1.x, wv1.y, whp0.z, wlp0.z);
        split2(wv1.z, wv1.w, whp0.w, wlp0.w);
        split2(wv2.x, wv2.y, whp1.x, wlp1.x);
        split2(wv2.z, wv2.w, whp1.y, wlp1.y);
        split2(wv3.x, wv3.y, whp1.z, wlp1.z);
        split2(wv3.z, wv3.w, whp1.w, wlp1.w);

        __syncthreads();
        sAhiF[a_idx] = ahp;
        sAloF[a_idx] = alp;
        sWhi[shalf][w_nt][((wq0 + 0) << 4) | w_n] = whp0;
        sWhi[shalf][w_nt][((wq0 + 1) << 4) | w_n] = whp1;
        sWlo[shalf][w_nt][((wq0 + 0) << 4) | w_n] = wlp0;
        sWlo[shalf][w_nt][((wq0 + 1) << 4) | w_n] = wlp1;
        __syncthreads();

        const bf16x8 ahi = *(const bf16x8*)&sAhi[whalf][wm][L * 2];
        const bf16x8 alo = *(const bf16x8*)&sAlo[whalf][wm][L * 2];
#pragma unroll
        for (int i = 0; i < 4; ++i) {
            const int nt = wn * 4 + i;
            const bf16x8 whi = *(const bf16x8*)&sWhi[whalf][nt][L];
            const bf16x8 wlo = *(const bf16x8*)&sWlo[whalf][nt][L];
            acc[i] = __builtin_amdgcn_mfma_f32_16x16x32_bf16(ahi, whi, acc[i], 0, 0, 0);
            acc[i] = __builtin_amdgcn_mfma_f32_16x16x32_bf16(ahi, wlo, acc[i], 0, 0, 0);
            acc[i] = __builtin_amdgcn_mfma_f32_16x16x32_bf16(alo, whi, acc[i], 0, 0, 0);
        }
    }

    __syncthreads();
    if (whalf == 0) {
#pragma unroll
        for (int i = 0; i < 4; ++i) {
            const int e = wn * 64 + i * 16 + (L & 15);
            const float b = bias[e];
#pragma unroll
            for (int r = 0; r < 4; ++r)
                sL[wm * 16 + (L >> 4) * 4 + r][e] = acc[i][r] + b;
        }
    }
    __syncthreads();
    if (whalf == 1) {
#pragma unroll
        for (int i = 0; i < 4; ++i) {
            const int e = wn * 64 + i * 16 + (L & 15);
#pragma unroll
            for (int r = 0; r < 4; ++r)
                sL[wm * 16 + (L >> 4) * 4 + r][e] += acc[i][r];
        }
    }
    __syncthreads();

    if (tid < MT) {
        float v0 = -1e30f, v1 = -1e30f, v2 = -1e30f, v3 = -1e30f, v4 = -1e30f;
        int   i0 = 0, i1 = 0, i2 = 0, i3 = 0, i4 = 0;
        for (int e = 0; e < E_EXP; ++e) {
            const float x = sL[tid][e];
            if (x > v4) {
                if (x > v0)      { v4=v3;i4=i3; v3=v2;i3=i2; v2=v1;i2=i1; v1=v0;i1=i0; v0=x;i0=e; }
                else if (x > v1) { v4=v3;i4=i3; v3=v2;i3=i2; v2=v1;i2=i1; v1=x;i1=e; }
                else if (x > v2) { v4=v3;i4=i3; v3=v2;i3=i2; v2=x;i2=e; }
                else if (x > v3) { v4=v3;i4=i3; v3=x;i3=e; }
                else             { v4=x;i4=e; }
            }
        }
        const float g0 = v0 - v1, g1 = v1 - v2, g2 = v2 - v3, g3 = v3 - v4;
        float mg = g0 < g1 ? g0 : g1;
        mg = mg < g2 ? mg : g2;
        mg = mg < g3 ? mg : g3;

        const float e0x = expf(v0 - v0);
        const float e1x = expf(v1 - v0);
        const float e2x = expf(v2 - v0);
        const float e3x = expf(v3 - v0);
        const float s   = e0x + e1x + e2x + e3x;

        const int gt = t_base + tid;
        float* out_scores = out;
        float* out_idx    = out + (size_t)T_TOKENS * TOPK;
        out_scores[gt * 4 + 0] = e0x / s;
        out_scores[gt * 4 + 1] = e1x / s;
        out_scores[gt * 4 + 2] = e2x / s;
        out_scores[gt * 4 + 3] = e3x / s;
        out_idx[gt * 4 + 0] = (float)i0;
        out_idx[gt * 4 + 1] = (float)i1;
        out_idx[gt * 4 + 2] = (float)i2;
        out_idx[gt * 4 + 3] = (float)i3;

        if (mg < EPS_GAP) {
            const int p = atomicAdd(flag_count, 1);
            if (p < T_TOKENS) flag_list[p] = gt;
        }
    }
}

// ---------------------------------------------------------------------------
// Fallback recheck (full 128-expert, reads A from global) — unchanged.
// ---------------------------------------------------------------------------
__global__ __launch_bounds__(256) void router_recheck_fb(
    const float* __restrict__ A, const float* __restrict__ W,
    const float* __restrict__ bias, float* __restrict__ out,
    const int* __restrict__ flag_count, const int* __restrict__ flag_list)
{
    __shared__ double sPart[256];
    __shared__ double sLog[E_EXP];

    int count = *flag_count;
    if (count > T_TOKENS) count = T_TOKENS;

    const int tid = threadIdx.x;
    const int e   = tid & (E_EXP - 1);
    const int h   = tid >> 7;

    for (int i = blockIdx.x; i < count; i += gridDim.x) {
        const int t = flag_list[i];
        const float* arow = A + (size_t)t * H_DIM + h * KHALF;
        const float* wrow = W + (size_t)e * H_DIM + h * KHALF;

        double s0 = 0.0, s1 = 0.0, s2 = 0.0, s3 = 0.0;
        float4 a[8], w[8];
#pragma unroll
        for (int q = 0; q < 8; ++q) {
            a[q] = *(const float4*)(arow + q * 4);
            w[q] = *(const float4*)(wrow + q * 4);
        }
        for (int it = 0; it < KHALF / 32 - 1; ++it) {
            const float* ap = arow + (it + 1) * 32;
            const float* wp = wrow + (it + 1) * 32;
            float4 na[8], nw[8];
#pragma unroll
            for (int q = 0; q < 8; ++q) {
                na[q] = *(const float4*)(ap + q * 4);
                nw[q] = *(const float4*)(wp + q * 4);
            }
#pragma unroll
            for (int q = 0; q < 8; ++q) {
                s0 += (double)a[q].x * (double)w[q].x;
                s1 += (double)a[q].y * (double)w[q].y;
                s2 += (double)a[q].z * (double)w[q].z;
                s3 += (double)a[q].w * (double)w[q].w;
            }
#pragma unroll
            for (int q = 0; q < 8; ++q) { a[q] = na[q]; w[q] = nw[q]; }
        }
#pragma unroll
        for (int q = 0; q < 8; ++q) {
            s0 += (double)a[q].x * (double)w[q].x;
            s1 += (double)a[q].y * (double)w[q].y;
            s2 += (double)a[q].z * (double)w[q].z;
            s3 += (double)a[q].w * (double)w[q].w;
        }
        sPart[tid] = (s0 + s1) + (s2 + s3);
        __syncthreads();
        if (h == 0) sLog[e] = sPart[e] + sPart[e + 128] + (double)bias[e];
        __syncthreads();

        if (tid == 0) {
            double v0 = -1e300, v1 = -1e300, v2 = -1e300, v3 = -1e300;
            int    i0 = 0, i1 = 0, i2 = 0, i3 = 0;
            for (int q = 0; q < E_EXP; ++q) {
                const double x = sLog[q];
                if (x > v3) {
                    if (x > v0)      { v3=v2;i3=i2; v2=v1;i2=i1; v1=v0;i1=i0; v0=x;i0=q; }
                    else if (x > v1) { v3=v2;i3=i2; v2=v1;i2=i1; v1=x;i1=q; }
                    else if (x > v2) { v3=v2;i3=i2; v2=x;i2=q; }
                    else             { v3=x;i3=q; }
                }
            }
            const double e0x = exp(v0 - v0);
            const double e1x = exp(v1 - v0);
            const double e2x = exp(v2 - v0);
            const double e3x = exp(v3 - v0);
            const double s   = e0x + e1x + e2x + e3x;
            float* out_scores = out;
            float* out_idx    = out + (size_t)T_TOKENS * TOPK;
            out_scores[t * 4 + 0] = (float)(e0x / s);
            out_scores[t * 4 + 1] = (float)(e1x / s);
            out_scores[t * 4 + 2] = (float)(e2x / s);
            out_scores[t * 4 + 3] = (float)(e3x / s);
            out_idx[t * 4 + 0] = (float)i0;
            out_idx[t * 4 + 1] = (float)i1;
            out_idx[t * 4 + 2] = (float)i2;
            out_idx[t * 4 + 3] = (float)i3;
        }
        __syncthreads();
    }
}

extern "C" void kernel_launch(void* const* d_in, const int* in_sizes, int n_in,
                              void* d_out, int out_size, void* d_ws, size_t ws_size,
                              hipStream_t stream) {
    const float* A    = (const float*)d_in[0];
    const float* W    = (const float*)d_in[1];
    const float* bias = (const float*)d_in[2];
    float* out = (float*)d_out;

    if (ws_size >= (size_t)WS_NEED) {
        int*   flag_count = (int*)d_ws;
        uint4* wsW        = (uint4*)((char*)d_ws + WS_WOFF);
        int*   flag_list  = (int*)((char*)d_ws + WS_FLOFF);
        uint2* cand_list  = (uint2*)((char*)d_ws + WS_CAOFF);
        hipMemsetAsync(flag_count, 0, sizeof(int), stream);
        prep_w<<<dim3((NCHUNK * 512) / 256), dim3(256), 0, stream>>>(W, wsW);
        router_main<<<dim3(T_TOKENS / MTM), dim3(1024), 0, stream>>>(
            A, wsW, bias, out, flag_count, flag_list, cand_list);
        router_recheck<<<dim3(512), dim3(256), 0, stream>>>(
            A, W, bias, out, flag_count, flag_list, cand_list);
    } else {
        int* flag_count = (int*)d_ws;
        int* flag_list  = (int*)d_ws + 1;
        hipMemsetAsync(flag_count, 0, sizeof(int), stream);
        router_main_fb<<<dim3(T_TOKENS / MT), dim3(512), 0, stream>>>(A, W, bias, out,
                                                                      flag_count, flag_list);
        router_recheck_fb<<<dim3(512), dim3(256), 0, stream>>>(A, W, bias, out,
                                                               flag_count, flag_list);
    }
}